// Round 9
// baseline (205.872 us; speedup 1.0000x reference)
//
#include <hip/hip_runtime.h>
#include <math.h>

// B=1, C=64, H=W=64, N=4096, heads=8, dh=8, inner=64, hid_lc=32, hid_f=256.
#define NPIX 4096
#define IMG 64

typedef __attribute__((ext_vector_type(8))) short bf16x8;
typedef __attribute__((ext_vector_type(4))) float floatx4;
typedef __attribute__((ext_vector_type(4))) unsigned int uintx4;

// fp32 -> (hi bf16 in low16) | (lo bf16 in high16), lo = x - f32(hi)
__device__ __forceinline__ unsigned int split_pack(float x) {
  unsigned int u = __float_as_uint(x);
  unsigned int hif = u & 0xffff0000u;
  float lof = x - __uint_as_float(hif);
  return (u >> 16) | (__float_as_uint(lof) & 0xffff0000u);
}

// pack hi16 of two floats: low16 = hi16(a), high16 = hi16(b)
__device__ __forceinline__ unsigned int hi_pair(float a, float b) {
  return (__float_as_uint(a) >> 16) | (__float_as_uint(b) & 0xffff0000u);
}

// ---------------------------------------------------------------------------
// lc1: h1[32][4096] = relu(conv3x3(luma)), thread = 1 px x 4 oc.
// grid (16 px-tiles, 8 ocg). ocg==0 blocks also emit pooled + tile sums;
// block (0,0) initializes the attn constant buffer.
__global__ __launch_bounds__(256) void lc1_kernel(
    const float* __restrict__ luma, const float* __restrict__ w1,
    const float* __restrict__ b1, float* __restrict__ h1,
    float* __restrict__ pooled, float* __restrict__ bsums,
    unsigned short* __restrict__ cbuf) {
  __shared__ float red[256];
  int tile = blockIdx.x, ocg = blockIdx.y;
  int tid = threadIdx.x;
  if (tile == 0 && ocg == 0 && tid < 16) cbuf[tid] = (tid < 8) ? 0x3F80 : 0;
  int p = tile * 256 + tid;
  int py = p >> 6, px = p & 63;
  float v[9];
#pragma unroll
  for (int dy = 0; dy < 3; dy++)
#pragma unroll
    for (int dx = 0; dx < 3; dx++) {
      int y = py + dy - 1, x = px + dx - 1;
      v[dy * 3 + dx] =
          (y >= 0 && y < IMG && x >= 0 && x < IMG) ? luma[y * IMG + x] : 0.f;
    }
#pragma unroll
  for (int o = 0; o < 4; o++) {
    int oc = ocg * 4 + o;
    float s = b1[oc];
#pragma unroll
    for (int t = 0; t < 9; t++) s = fmaf(w1[oc * 9 + t], v[t], s);
    h1[oc * NPIX + p] = fmaxf(s, 0.f);
  }
  if (ocg == 0) {
    float sv = 0.f;
#pragma unroll
    for (int t = 0; t < 9; t++) sv += v[t];
    float cy = 3.f - (py == 0 ? 1.f : 0.f) - (py == 63 ? 1.f : 0.f);
    float cx = 3.f - (px == 0 ? 1.f : 0.f) - (px == 63 ? 1.f : 0.f);
    float pv = (cy * cx - sv) * (1.f / 9.f);
    pooled[p] = pv;
    red[tid] = pv;
    __syncthreads();
    for (int st = 128; st > 0; st >>= 1) {
      if (tid < st) red[tid] += red[tid + st];
      __syncthreads();
    }
    if (tid == 0) bsums[tile] = red[0];
  }
}

// ---------------------------------------------------------------------------
// lc2: h2[32][4096] = relu(conv3x3(h1)), halo staged from global.
// ocg==0 blocks also compute per-pixel LN1 stats of x (mu1, rs1).
// grid (16 px-tiles of 16x16, 8 ocg of 4).
__global__ __launch_bounds__(256) void lc2_kernel(
    const float* __restrict__ h1, const float* __restrict__ w2,
    const float* __restrict__ b2, const float* __restrict__ x,
    float* __restrict__ h2, float* __restrict__ mu1, float* __restrict__ rs1) {
  __shared__ float tin[32][324];  // 18x18 halo per ic
  __shared__ float swt[4][32][9];
  int tile = blockIdx.x, ocg = blockIdx.y;
  int ty0 = (tile >> 2) * 16, tx0 = (tile & 3) * 16;
  int tid = threadIdx.x;
  for (int idx = tid; idx < 32 * 324; idx += 256) {
    int ic = idx / 324, pos = idx - ic * 324;
    int py = pos / 18, px = pos - py * 18;
    int gy = ty0 + py - 1, gx = tx0 + px - 1;
    tin[ic][pos] = (gy >= 0 && gy < IMG && gx >= 0 && gx < IMG)
                       ? h1[ic * NPIX + gy * IMG + gx]
                       : 0.f;
  }
  for (int idx = tid; idx < 4 * 32 * 9; idx += 256) {
    int o = idx / 288, r = idx - o * 288;
    swt[o][r / 9][r % 9] = w2[(ocg * 4 + o) * 288 + r];
  }
  __syncthreads();
  int ly = tid >> 4, lx = tid & 15;
  int p = (ty0 + ly) * IMG + tx0 + lx;
  float acc[4];
#pragma unroll
  for (int o = 0; o < 4; o++) acc[o] = b2[ocg * 4 + o];
  for (int ic = 0; ic < 32; ic++) {
    float v[9];
#pragma unroll
    for (int dy = 0; dy < 3; dy++)
#pragma unroll
      for (int dx = 0; dx < 3; dx++)
        v[dy * 3 + dx] = tin[ic][(ly + dy) * 18 + lx + dx];
#pragma unroll
    for (int o = 0; o < 4; o++)
#pragma unroll
      for (int t = 0; t < 9; t++) acc[o] = fmaf(swt[o][ic][t], v[t], acc[o]);
  }
#pragma unroll
  for (int o = 0; o < 4; o++)
    h2[(ocg * 4 + o) * NPIX + p] = fmaxf(acc[o], 0.f);
  if (ocg == 0) {
    float s = 0.f, q = 0.f;
#pragma unroll 8
    for (int cc = 0; cc < 64; cc++) {
      float xv = x[cc * NPIX + p];
      s += xv;
      q = fmaf(xv, xv, q);
    }
    float mu = s * (1.f / 64.f);
    mu1[p] = mu;
    rs1[p] = rsqrtf(q * (1.f / 64.f) - mu * mu + 1e-5f);
  }
}

// ---------------------------------------------------------------------------
// Fused per-pixel LayerNorm (precomputed stats) + qkv 1x1 GEMM + (gam/bet
// GEMMs in-register) + modulation + hi/lo split store. grid (64, 3).
__global__ __launch_bounds__(256) void ln_qkv_kernel(
    const float* __restrict__ X, const float* __restrict__ mu1,
    const float* __restrict__ rs1, const float* __restrict__ lnw,
    const float* __restrict__ lnb, const float* __restrict__ W,
    const float* __restrict__ bias, const float* __restrict__ gamW,
    const float* __restrict__ gamB, const float* __restrict__ betW,
    const float* __restrict__ betB, const float* __restrict__ h2,
    const float* __restrict__ pooled, const float* __restrict__ bsums,
    const float* __restrict__ alpha, unsigned short* __restrict__ qhl,
    unsigned short* __restrict__ khl, unsigned short* __restrict__ vthx,
    unsigned short* __restrict__ vtlx) {
  const float QSCALE = 0.35355339059327376f * 1.4426950408889634f;
  __shared__ float xs[64][64];
  __shared__ float wsh[64][64];
  __shared__ float h2s[32][64];
  __shared__ float wgs[32][64];
  __shared__ float wbs[32][64];
  __shared__ float mu[64];
  __shared__ float rs[64];
  int n0 = blockIdx.x * 64, part = blockIdx.y, m0 = part * 64;
  int tid = threadIdx.x;
  int c = tid >> 2, pg = (tid & 3) * 16;
  if (tid < 64) {
    mu[tid] = mu1[n0 + tid];
    rs[tid] = rs1[n0 + tid];
  }
  {
    const float4* src = (const float4*)&X[c * NPIX + n0 + pg];
    float4* dst = (float4*)&xs[c][pg];
    dst[0] = src[0]; dst[1] = src[1]; dst[2] = src[2]; dst[3] = src[3];
  }
  {
    int m = tid >> 2, kg = (tid & 3) * 16;
    const float4* wr = (const float4*)&W[(m0 + m) * 64 + kg];
    float4 w0 = wr[0], w1 = wr[1], w2 = wr[2], w3 = wr[3];
    float wv[16] = {w0.x, w0.y, w0.z, w0.w, w1.x, w1.y, w1.z, w1.w,
                    w2.x, w2.y, w2.z, w2.w, w3.x, w3.y, w3.z, w3.w};
#pragma unroll
    for (int j = 0; j < 16; j++) wsh[kg + j][m] = wv[j];
  }
  {
    int i0 = tid * 2;
    int k = i0 >> 4, nf = (i0 & 15) * 4;
    *(float4*)&h2s[k][nf] = *(const float4*)&h2[k * NPIX + n0 + nf];
    int i1 = i0 + 1;
    int k1 = i1 >> 4, nf1 = (i1 & 15) * 4;
    *(float4*)&h2s[k1][nf1] = *(const float4*)&h2[k1 * NPIX + n0 + nf1];
  }
  {
    int m = tid >> 2, kg = (tid & 3) * 8;
    const float4* g0 = (const float4*)&gamW[m * 32 + kg];
    float4 a = g0[0], b4 = g0[1];
    float gv[8] = {a.x, a.y, a.z, a.w, b4.x, b4.y, b4.z, b4.w};
#pragma unroll
    for (int j = 0; j < 8; j++) wgs[kg + j][m] = gv[j];
    const float4* bb0 = (const float4*)&betW[m * 32 + kg];
    float4 c4 = bb0[0], d4 = bb0[1];
    float bv[8] = {c4.x, c4.y, c4.z, c4.w, d4.x, d4.y, d4.z, d4.w};
#pragma unroll
    for (int j = 0; j < 8; j++) wbs[kg + j][m] = bv[j];
  }
  __syncthreads();
  {
    float wc = lnw[c], bc = lnb[c];
#pragma unroll
    for (int j = 0; j < 16; j++) {
      int p = pg + j;
      xs[c][p] = (xs[c][p] - mu[p]) * rs[p] * wc + bc;
    }
  }
  __syncthreads();
  int tx = tid & 15, ty = tid >> 4;
  float ga[4][4] = {}, ba[4][4] = {};
#pragma unroll 8
  for (int kk = 0; kk < 32; kk++) {
    float4 wg4 = *(const float4*)&wgs[kk][ty * 4];
    float4 wb4 = *(const float4*)&wbs[kk][ty * 4];
    float4 h24 = *(const float4*)&h2s[kk][tx * 4];
    float gv[4] = {wg4.x, wg4.y, wg4.z, wg4.w};
    float bv[4] = {wb4.x, wb4.y, wb4.z, wb4.w};
    float hv[4] = {h24.x, h24.y, h24.z, h24.w};
#pragma unroll
    for (int im = 0; im < 4; im++)
#pragma unroll
      for (int in = 0; in < 4; in++) {
        ga[im][in] = fmaf(gv[im], hv[in], ga[im][in]);
        ba[im][in] = fmaf(bv[im], hv[in], ba[im][in]);
      }
  }
#pragma unroll
  for (int im = 0; im < 4; im++) {
    int cc = ty * 4 + im;
    float gb = gamB[cc], bb2 = betB[cc];
#pragma unroll
    for (int in = 0; in < 4; in++) {
      ga[im][in] += gb;
      ba[im][in] += bb2;
    }
  }
  float acc[4][4] = {};
#pragma unroll 8
  for (int kk = 0; kk < 64; kk++) {
    float4 a = *(const float4*)&wsh[kk][ty * 4];
    float4 b4 = *(const float4*)&xs[kk][tx * 4];
    float av[4] = {a.x, a.y, a.z, a.w};
    float bv[4] = {b4.x, b4.y, b4.z, b4.w};
#pragma unroll
    for (int im = 0; im < 4; im++)
#pragma unroll
      for (int in = 0; in < 4; in++)
        acc[im][in] = fmaf(av[im], bv[in], acc[im][in]);
  }
  float val[4][4];
#pragma unroll
  for (int im = 0; im < 4; im++) {
    int cc = ty * 4 + im;
    float bv = bias[m0 + cc];
#pragma unroll
    for (int in = 0; in < 4; in++)
      val[im][in] = fmaf(ga[im][in], acc[im][in] + bv, ba[im][in]);
  }
  if (part == 0) {
    float msum = 0.f;
#pragma unroll
    for (int t = 0; t < 16; t++) msum += bsums[t];
    float mean = msum * (1.f / 4096.f);
    float a0 = alpha[0];
    const float4 pv = *(const float4*)&pooled[n0 + tx * 4];
    float iv[4] = {a0 * (pv.x - mean), a0 * (pv.y - mean),
                   a0 * (pv.z - mean), a0 * (pv.w - mean)};
#pragma unroll
    for (int im = 0; im < 4; im++)
#pragma unroll
      for (int in = 0; in < 4; in++)
        val[im][in] = (val[im][in] + iv[in]) * QSCALE;
  }
  if (part < 2) {
    unsigned short* dst = (part == 0) ? qhl : khl;
    int h = ty >> 1, d0 = (ty & 1) * 4;
#pragma unroll
    for (int in = 0; in < 4; in++) {
      int n = n0 + tx * 4 + in;
      unsigned int pk[4];
#pragma unroll
      for (int im = 0; im < 4; im++) pk[im] = split_pack(val[im][in]);
      short4 hi, lo;
      hi.x = (short)(pk[0] & 0xffffu); hi.y = (short)(pk[1] & 0xffffu);
      hi.z = (short)(pk[2] & 0xffffu); hi.w = (short)(pk[3] & 0xffffu);
      lo.x = (short)(pk[0] >> 16); lo.y = (short)(pk[1] >> 16);
      lo.z = (short)(pk[2] >> 16); lo.w = (short)(pk[3] >> 16);
      unsigned short* base = dst + ((size_t)(h * NPIX + n) << 4) + d0;
      *(short4*)base = hi;
      *(short4*)(base + 8) = lo;
    }
  } else {
    int nq = n0 + tx * 4;
    int off0 = (nq >> 5) * 32 + ((nq >> 4) & 1) * 4 + ((nq >> 2) & 3) * 8;
#pragma unroll
    for (int im = 0; im < 4; im++) {
      int cc = ty * 4 + im;
      unsigned int pk[4];
#pragma unroll
      for (int in = 0; in < 4; in++) pk[in] = split_pack(val[im][in]);
      short4 hi, lo;
      hi.x = (short)(pk[0] & 0xffffu); hi.y = (short)(pk[1] & 0xffffu);
      hi.z = (short)(pk[2] & 0xffffu); hi.w = (short)(pk[3] & 0xffffu);
      lo.x = (short)(pk[0] >> 16); lo.y = (short)(pk[1] >> 16);
      lo.z = (short)(pk[2] >> 16); lo.w = (short)(pk[3] >> 16);
      *(short4*)(vthx + (size_t)cc * NPIX + off0) = hi;
      *(short4*)(vtlx + (size_t)cc * NPIX + off0) = lo;
    }
  }
}

// ---------------------------------------------------------------------------
// MFMA flash attention. JP=8 partitions (512 j each), 2 i-tiles per wave,
// 6 waves/SIMD. grid (32 i-tiles of 128, 8 heads, 8 jp).
__global__ __launch_bounds__(256, 6) void attn_kernel(
    const unsigned short* __restrict__ qhl,
    const unsigned short* __restrict__ khl,
    const unsigned short* __restrict__ vthx,
    const unsigned short* __restrict__ vtlx,
    const unsigned short* __restrict__ cbuf, float* __restrict__ pacc,
    float* __restrict__ pl) {
  int tid = threadIdx.x;
  int wave = tid >> 6, lane = tid & 63;
  int g = lane >> 4, c = lane & 15;
  int h = blockIdx.y, jp = blockIdx.z;
  int i0 = blockIdx.x * 128 + wave * 32;
  int jbase = jp * 512;
  const bf16x8 qB0 = *(const bf16x8*)(qhl + ((size_t)(h * NPIX + i0 + c) << 4) +
                                      ((g & 1) << 3));
  const bf16x8 qB1 = *(const bf16x8*)(
      qhl + ((size_t)(h * NPIX + i0 + 16 + c) << 4) + ((g & 1) << 3));
  const unsigned short* kp =
      khl + ((size_t)(h * NPIX + jbase + c) << 4) + ((g >> 1) << 3);
  const unsigned short* vhp;
  const unsigned short* vlp;
  int vstep;
  if (c < 8) {
    vhp = vthx + (size_t)(h * 8 + c) * NPIX + jbase + (g << 3);
    vlp = vtlx + (size_t)(h * 8 + c) * NPIX + jbase + (g << 3);
    vstep = 32;
  } else {
    vhp = (c == 8) ? cbuf : (cbuf + 8);  // ones row / zero rows
    vlp = cbuf + 8;
    vstep = 0;
  }
  floatx4 zero4 = {0.f, 0.f, 0.f, 0.f};
  floatx4 aH0 = zero4, aM0 = zero4, aH1 = zero4, aM1 = zero4;
#pragma unroll 2
  for (int jt = 0; jt < 16; ++jt) {
    bf16x8 ka0 = *(const bf16x8*)kp;
    bf16x8 ka1 = *(const bf16x8*)(kp + 256);
    bf16x8 avh = *(const bf16x8*)vhp;
    bf16x8 avl = *(const bf16x8*)vlp;
    kp += 512;
    vhp += vstep;
    vlp += vstep;
    floatx4 s00 =
        __builtin_amdgcn_mfma_f32_16x16x32_bf16(ka0, qB0, zero4, 0, 0, 0);
    floatx4 s01 =
        __builtin_amdgcn_mfma_f32_16x16x32_bf16(ka1, qB0, zero4, 0, 0, 0);
    floatx4 s10 =
        __builtin_amdgcn_mfma_f32_16x16x32_bf16(ka0, qB1, zero4, 0, 0, 0);
    floatx4 s11 =
        __builtin_amdgcn_mfma_f32_16x16x32_bf16(ka1, qB1, zero4, 0, 0, 0);
    {
      float p0 = __builtin_amdgcn_exp2f(fminf(s00[0], 80.f));
      float p1 = __builtin_amdgcn_exp2f(fminf(s00[1], 80.f));
      float p2 = __builtin_amdgcn_exp2f(fminf(s00[2], 80.f));
      float p3 = __builtin_amdgcn_exp2f(fminf(s00[3], 80.f));
      float p4 = __builtin_amdgcn_exp2f(fminf(s01[0], 80.f));
      float p5 = __builtin_amdgcn_exp2f(fminf(s01[1], 80.f));
      float p6 = __builtin_amdgcn_exp2f(fminf(s01[2], 80.f));
      float p7 = __builtin_amdgcn_exp2f(fminf(s01[3], 80.f));
      uintx4 bh;
      bh.x = hi_pair(p0, p1);
      bh.y = hi_pair(p2, p3);
      bh.z = hi_pair(p4, p5);
      bh.w = hi_pair(p6, p7);
      bf16x8 pbh = __builtin_bit_cast(bf16x8, bh);
      aH0 = __builtin_amdgcn_mfma_f32_16x16x32_bf16(avh, pbh, aH0, 0, 0, 0);
      aM0 = __builtin_amdgcn_mfma_f32_16x16x32_bf16(avl, pbh, aM0, 0, 0, 0);
    }
    {
      float p0 = __builtin_amdgcn_exp2f(fminf(s10[0], 80.f));
      float p1 = __builtin_amdgcn_exp2f(fminf(s10[1], 80.f));
      float p2 = __builtin_amdgcn_exp2f(fminf(s10[2], 80.f));
      float p3 = __builtin_amdgcn_exp2f(fminf(s10[3], 80.f));
      float p4 = __builtin_amdgcn_exp2f(fminf(s11[0], 80.f));
      float p5 = __builtin_amdgcn_exp2f(fminf(s11[1], 80.f));
      float p6 = __builtin_amdgcn_exp2f(fminf(s11[2], 80.f));
      float p7 = __builtin_amdgcn_exp2f(fminf(s11[3], 80.f));
      uintx4 bh;
      bh.x = hi_pair(p0, p1);
      bh.y = hi_pair(p2, p3);
      bh.z = hi_pair(p4, p5);
      bh.w = hi_pair(p6, p7);
      bf16x8 pbh = __builtin_bit_cast(bf16x8, bh);
      aH1 = __builtin_amdgcn_mfma_f32_16x16x32_bf16(avh, pbh, aH1, 0, 0, 0);
      aM1 = __builtin_amdgcn_mfma_f32_16x16x32_bf16(avl, pbh, aM1, 0, 0, 0);
    }
  }
  floatx4 o0 = aH0 + aM0;
  floatx4 o1 = aH1 + aM1;
  if (g < 2) {
    size_t b0 = (size_t)((jp * 8 + h) * NPIX + i0 + c);
    *(float4*)&pacc[b0 * 8 + g * 4] = make_float4(o0[0], o0[1], o0[2], o0[3]);
    size_t b1 = b0 + 16;
    *(float4*)&pacc[b1 * 8 + g * 4] = make_float4(o1[0], o1[1], o1[2], o1[3]);
  } else if (g == 2) {
    pl[(size_t)((jp * 8 + h) * NPIX + i0 + c)] = o0[0];
    pl[(size_t)((jp * 8 + h) * NPIX + i0 + 16 + c)] = o1[0];
  }
}

// ---------------------------------------------------------------------------
// Fused: combine 8 j-partitions -> proj GEMM + residual -> x1 (ch==0) + LN2
// stats -> LN -> one 64-ch slice of ffn1 -> f1. grid (128, 4).
__global__ __launch_bounds__(256) void proj_ffn1_kernel(
    const float* __restrict__ pacc, const float* __restrict__ pl,
    const float* __restrict__ Wp, const float* __restrict__ bp,
    const float* __restrict__ x, const float* __restrict__ ln2w,
    const float* __restrict__ ln2b, const float* __restrict__ W1,
    const float* __restrict__ b1f, float* __restrict__ x1,
    float* __restrict__ f1) {
  __shared__ float at[64][33];
  __shared__ float wsh[64][64];
  __shared__ float xsl[64][33];
  __shared__ float ps[8][33];
  __shared__ float pq[8][33];
  __shared__ float mus[32];
  __shared__ float rss[32];
  int n0 = blockIdx.x * 32;
  int ch = blockIdx.y;
  int tid = threadIdx.x;
  {
    int mm = tid >> 2, kg = (tid & 3) * 16;
    const float4* wr = (const float4*)&Wp[mm * 64 + kg];
    float4 w0 = wr[0], w1 = wr[1], w2 = wr[2], w3 = wr[3];
    float wv[16] = {w0.x, w0.y, w0.z, w0.w, w1.x, w1.y, w1.z, w1.w,
                    w2.x, w2.y, w2.z, w2.w, w3.x, w3.y, w3.z, w3.w};
#pragma unroll
    for (int j = 0; j < 16; j++) wsh[kg + j][mm] = wv[j];
  }
  {
    int hh = tid >> 5, nn = tid & 31;
    int i = n0 + nn;
    float L = 0.f, o[8] = {};
#pragma unroll
    for (int p = 0; p < 8; p++) {
      size_t base = (size_t)((p * 8 + hh) * NPIX + i);
      L += pl[base];
      const float4 a0 = *(const float4*)&pacc[base * 8];
      const float4 a1 = *(const float4*)&pacc[base * 8 + 4];
      o[0] += a0.x; o[1] += a0.y; o[2] += a0.z; o[3] += a0.w;
      o[4] += a1.x; o[5] += a1.y; o[6] += a1.z; o[7] += a1.w;
    }
    float inv = 1.f / L;
#pragma unroll
    for (int d = 0; d < 8; d++) at[hh * 8 + d][nn] = o[d] * inv;
  }
  __syncthreads();
  int ty = tid >> 5, tx = tid & 31;
  float acc[8] = {};
#pragma unroll 8
  for (int k = 0; k < 64; k++) {
    float b = at[k][tx];
    float4 a0 = *(const float4*)&wsh[k][ty * 8];
    float4 a1 = *(const float4*)&wsh[k][ty * 8 + 4];
    acc[0] = fmaf(a0.x, b, acc[0]);
    acc[1] = fmaf(a0.y, b, acc[1]);
    acc[2] = fmaf(a0.z, b, acc[2]);
    acc[3] = fmaf(a0.w, b, acc[3]);
    acc[4] = fmaf(a1.x, b, acc[4]);
    acc[5] = fmaf(a1.y, b, acc[5]);
    acc[6] = fmaf(a1.z, b, acc[6]);
    acc[7] = fmaf(a1.w, b, acc[7]);
  }
  float v[8], sn = 0.f, qn = 0.f;
#pragma unroll
  for (int im = 0; im < 8; im++) {
    int row = ty * 8 + im;
    float vv = acc[im] + bp[row] + x[row * NPIX + n0 + tx];
    v[im] = vv;
    sn += vv;
    qn = fmaf(vv, vv, qn);
  }
  if (ch == 0) {
#pragma unroll
    for (int im = 0; im < 8; im++)
      x1[(ty * 8 + im) * NPIX + n0 + tx] = v[im];
  }
  ps[ty][tx] = sn;
  pq[ty][tx] = qn;
  __syncthreads();
  if (tid < 32) {
    float s = 0.f, q = 0.f;
#pragma unroll
    for (int t = 0; t < 8; t++) {
      s += ps[t][tid];
      q += pq[t][tid];
    }
    float mu = s * (1.f / 64.f);
    mus[tid] = mu;
    rss[tid] = rsqrtf(q * (1.f / 64.f) - mu * mu + 1e-5f);
  }
  __syncthreads();
  {
    float muv = mus[tx], rsv = rss[tx];
#pragma unroll
    for (int im = 0; im < 8; im++) {
      int row = ty * 8 + im;
      xsl[row][tx] = (v[im] - muv) * rsv * ln2w[row] + ln2b[row];
    }
  }
  {
    int mm = tid >> 2, kg = (tid & 3) * 16;
    const float4* wr = (const float4*)&W1[(ch * 64 + mm) * 64 + kg];
    float4 w0 = wr[0], w1 = wr[1], w2 = wr[2], w3 = wr[3];
    float wv[16] = {w0.x, w0.y, w0.z, w0.w, w1.x, w1.y, w1.z, w1.w,
                    w2.x, w2.y, w2.z, w2.w, w3.x, w3.y, w3.z, w3.w};
#pragma unroll
    for (int j = 0; j < 16; j++) wsh[kg + j][mm] = wv[j];
  }
  __syncthreads();
  float a2[8] = {};
#pragma unroll 8
  for (int k = 0; k < 64; k++) {
    float b = xsl[k][tx];
    float4 a0 = *(const float4*)&wsh[k][ty * 8];
    float4 a1 = *(const float4*)&wsh[k][ty * 8 + 4];
    a2[0] = fmaf(a0.x, b, a2[0]);
    a2[1] = fmaf(a0.y, b, a2[1]);
    a2[2] = fmaf(a0.z, b, a2[2]);
    a2[3] = fmaf(a0.w, b, a2[3]);
    a2[4] = fmaf(a1.x, b, a2[4]);
    a2[5] = fmaf(a1.y, b, a2[5]);
    a2[6] = fmaf(a1.z, b, a2[6]);
    a2[7] = fmaf(a1.w, b, a2[7]);
  }
#pragma unroll
  for (int im = 0; im < 8; im++) {
    int row = ch * 64 + ty * 8 + im;
    f1[row * NPIX + n0 + tx] = a2[im] + b1f[row];
  }
}

// ---------------------------------------------------------------------------
// Depthwise 3x3 + exact GELU; 4 horizontal px/thread (unchanged).
__global__ __launch_bounds__(256) void dw_gelu_kernel(
    const float* __restrict__ f1, const float* __restrict__ w,
    const float* __restrict__ b, float* __restrict__ f2) {
  int t = blockIdx.x * 256 + threadIdx.x;
  int c = t >> 10, pq = t & 1023;
  int py = pq >> 4, px0 = (pq & 15) << 2;
  const float* base = f1 + c * NPIX;
  float wv[9];
#pragma unroll
  for (int i = 0; i < 9; i++) wv[i] = w[c * 9 + i];
  float bc = b[c];
  float a[4] = {bc, bc, bc, bc};
#pragma unroll
  for (int dy = 0; dy < 3; dy++) {
    int y = py + dy - 1;
    if (y < 0 || y > 63) continue;
    const float* row = base + y * IMG + px0;
    float4 mid = *(const float4*)row;
    float left = (px0 > 0) ? row[-1] : 0.f;
    float right = (px0 < 60) ? row[4] : 0.f;
    float win[6] = {left, mid.x, mid.y, mid.z, mid.w, right};
#pragma unroll
    for (int o = 0; o < 4; o++)
#pragma unroll
      for (int dx = 0; dx < 3; dx++)
        a[o] = fmaf(wv[dy * 3 + dx], win[o + dx], a[o]);
  }
  float4 o4;
  float* op = &o4.x;
#pragma unroll
  for (int o = 0; o < 4; o++)
    op[o] = 0.5f * a[o] * (1.f + erff(a[o] * 0.70710678118654752f));
  *(float4*)&f2[c * NPIX + py * IMG + px0] = o4;
}

// ---------------------------------------------------------------------------
// ffn2 GEMM: out = W[64][256] * f2 + bias + x1 (residual). (unchanged)
__global__ __launch_bounds__(256) void gemm16_kernel(
    const float* __restrict__ W, const float* __restrict__ X,
    const float* __restrict__ bias, const float* __restrict__ resid,
    float* __restrict__ C, int K) {
  __shared__ float xs[32][64];
  __shared__ float wsh[32][16];
  int n0 = blockIdx.x * 64, m0 = blockIdx.y * 16;
  int tid = threadIdx.x;
  int m = tid >> 4, ng = tid & 15;
  float acc[4] = {};
  for (int k0 = 0; k0 < K; k0 += 32) {
    {
      int i0 = tid * 2;
      int k = i0 >> 4, nf = (i0 & 15) * 4;
      *(float4*)&xs[k][nf] = *(const float4*)&X[(k0 + k) * NPIX + n0 + nf];
      int i1 = i0 + 1;
      int k1 = i1 >> 4, nf1 = (i1 & 15) * 4;
      *(float4*)&xs[k1][nf1] = *(const float4*)&X[(k0 + k1) * NPIX + n0 + nf1];
    }
#pragma unroll
    for (int e = tid; e < 512; e += 256) {
      int mm = e >> 5, kk = e & 31;
      wsh[kk][mm] = W[(m0 + mm) * K + k0 + kk];
    }
    __syncthreads();
#pragma unroll 8
    for (int kk = 0; kk < 32; kk++) {
      float a = wsh[kk][m];
      float4 b4 = *(const float4*)&xs[kk][ng * 4];
      acc[0] = fmaf(a, b4.x, acc[0]);
      acc[1] = fmaf(a, b4.y, acc[1]);
      acc[2] = fmaf(a, b4.z, acc[2]);
      acc[3] = fmaf(a, b4.w, acc[3]);
    }
    __syncthreads();
  }
  int row = m0 + m;
  float bv = bias[row];
  float4 o = make_float4(acc[0] + bv, acc[1] + bv, acc[2] + bv, acc[3] + bv);
  const float4 r4 = *(const float4*)&resid[row * NPIX + n0 + ng * 4];
  o.x += r4.x; o.y += r4.y; o.z += r4.z; o.w += r4.w;
  *(float4*)&C[row * NPIX + n0 + ng * 4] = o;
}

// ---------------------------------------------------------------------------
extern "C" void kernel_launch(void* const* d_in, const int* in_sizes, int n_in,
                              void* d_out, int out_size, void* d_ws,
                              size_t ws_size, hipStream_t stream) {
  const float* x      = (const float*)d_in[0];
  const float* luma   = (const float*)d_in[1];
  const float* ln1_w  = (const float*)d_in[2];
  const float* ln1_b  = (const float*)d_in[3];
  const float* qkv_w  = (const float*)d_in[4];
  const float* qkv_b  = (const float*)d_in[5];
  const float* proj_w = (const float*)d_in[6];
  const float* proj_b = (const float*)d_in[7];
  const float* lc1_w  = (const float*)d_in[8];
  const float* lc1_b  = (const float*)d_in[9];
  const float* lc2_w  = (const float*)d_in[10];
  const float* lc2_b  = (const float*)d_in[11];
  const float* gam_w  = (const float*)d_in[12];
  const float* gam_b  = (const float*)d_in[13];
  const float* bet_w  = (const float*)d_in[14];
  const float* bet_b  = (const float*)d_in[15];
  const float* alpha  = (const float*)d_in[16];
  const float* ln2_w  = (const float*)d_in[17];
  const float* ln2_b  = (const float*)d_in[18];
  const float* ffn1_w = (const float*)d_in[19];
  const float* ffn1_b = (const float*)d_in[20];
  const float* dw_w   = (const float*)d_in[21];
  const float* dw_b   = (const float*)d_in[22];
  const float* ffn2_w = (const float*)d_in[23];
  const float* ffn2_b = (const float*)d_in[24];
  float* out = (float*)d_out;

  float* w = (float*)d_ws;
  float* pooled = w + 0;        // 4096
  float* bsums  = w + 4096;     // 64 (16 used)
  unsigned short* cbuf = (unsigned short*)(w + 4160);     // 64 f (16 us used)
  float* mu1 = w + 4224;        // 4096
  float* rs1 = w + 8320;        // 4096
  unsigned short* qhl  = (unsigned short*)(w + 12416);    // 262144 f
  unsigned short* khl  = (unsigned short*)(w + 274560);   // 262144 f
  unsigned short* vthx = (unsigned short*)(w + 536704);   // 131072 f
  unsigned short* vtlx = (unsigned short*)(w + 667776);   // 131072 f
  float* pacc = w + 798848;    // 2097152 (JP=8)
  float* pl   = w + 2896000;   // 262144
  float* x1   = w + 3158144;   // 262144
  float* f1   = w + 3420288;   // 1048576
  float* f2   = w + 4468864;   // 1048576
  float* h2   = w + 5517440;   // 131072
  float* h1   = w + 5648512;   // 131072

  lc1_kernel<<<dim3(16, 8), 256, 0, stream>>>(luma, lc1_w, lc1_b, h1, pooled,
                                              bsums, cbuf);
  lc2_kernel<<<dim3(16, 8), 256, 0, stream>>>(h1, lc2_w, lc2_b, x, h2, mu1,
                                              rs1);
  ln_qkv_kernel<<<dim3(64, 3), 256, 0, stream>>>(
      x, mu1, rs1, ln1_w, ln1_b, qkv_w, qkv_b, gam_w, gam_b, bet_w, bet_b, h2,
      pooled, bsums, alpha, qhl, khl, vthx, vtlx);
  attn_kernel<<<dim3(32, 8, 8), 256, 0, stream>>>(qhl, khl, vthx, vtlx, cbuf,
                                                  pacc, pl);
  proj_ffn1_kernel<<<dim3(128, 4), 256, 0, stream>>>(
      pacc, pl, proj_w, proj_b, x, ln2_w, ln2_b, ffn1_w, ffn1_b, x1, f1);
  dw_gelu_kernel<<<1024, 256, 0, stream>>>(f1, dw_w, dw_b, f2);
  gemm16_kernel<<<dim3(64, 4), 256, 0, stream>>>(ffn2_w, f2, ffn2_b, x1, out,
                                                 256);
}

// Round 10
// 202.599 us; speedup vs baseline: 1.0162x; 1.0162x over previous
//
#include <hip/hip_runtime.h>
#include <math.h>

// B=1, C=64, H=W=64, N=4096, heads=8, dh=8, inner=64, hid_lc=32, hid_f=256.
#define NPIX 4096
#define IMG 64

typedef __attribute__((ext_vector_type(8))) short bf16x8;
typedef __attribute__((ext_vector_type(4))) float floatx4;
typedef __attribute__((ext_vector_type(4))) unsigned int uintx4;

// fp32 -> (hi bf16 in low16) | (lo bf16 in high16), lo = x - f32(hi)
__device__ __forceinline__ unsigned int split_pack(float x) {
  unsigned int u = __float_as_uint(x);
  unsigned int hif = u & 0xffff0000u;
  float lof = x - __uint_as_float(hif);
  return (u >> 16) | (__float_as_uint(lof) & 0xffff0000u);
}

// pack hi16 of two floats: low16 = hi16(a), high16 = hi16(b)
__device__ __forceinline__ unsigned int hi_pair(float a, float b) {
  return (__float_as_uint(a) >> 16) | (__float_as_uint(b) & 0xffff0000u);
}

// ---------------------------------------------------------------------------
// lc1: h1[32][4096] = relu(conv3x3(luma)), thread = 1 px x 4 oc.
__global__ __launch_bounds__(256) void lc1_kernel(
    const float* __restrict__ luma, const float* __restrict__ w1,
    const float* __restrict__ b1, float* __restrict__ h1,
    float* __restrict__ pooled, float* __restrict__ bsums,
    unsigned short* __restrict__ cbuf) {
  __shared__ float red[256];
  int tile = blockIdx.x, ocg = blockIdx.y;
  int tid = threadIdx.x;
  if (tile == 0 && ocg == 0 && tid < 16) cbuf[tid] = (tid < 8) ? 0x3F80 : 0;
  int p = tile * 256 + tid;
  int py = p >> 6, px = p & 63;
  float v[9];
#pragma unroll
  for (int dy = 0; dy < 3; dy++)
#pragma unroll
    for (int dx = 0; dx < 3; dx++) {
      int y = py + dy - 1, x = px + dx - 1;
      v[dy * 3 + dx] =
          (y >= 0 && y < IMG && x >= 0 && x < IMG) ? luma[y * IMG + x] : 0.f;
    }
#pragma unroll
  for (int o = 0; o < 4; o++) {
    int oc = ocg * 4 + o;
    float s = b1[oc];
#pragma unroll
    for (int t = 0; t < 9; t++) s = fmaf(w1[oc * 9 + t], v[t], s);
    h1[oc * NPIX + p] = fmaxf(s, 0.f);
  }
  if (ocg == 0) {
    float sv = 0.f;
#pragma unroll
    for (int t = 0; t < 9; t++) sv += v[t];
    float cy = 3.f - (py == 0 ? 1.f : 0.f) - (py == 63 ? 1.f : 0.f);
    float cx = 3.f - (px == 0 ? 1.f : 0.f) - (px == 63 ? 1.f : 0.f);
    float pv = (cy * cx - sv) * (1.f / 9.f);
    pooled[p] = pv;
    red[tid] = pv;
    __syncthreads();
    for (int st = 128; st > 0; st >>= 1) {
      if (tid < st) red[tid] += red[tid + st];
      __syncthreads();
    }
    if (tid == 0) bsums[tile] = red[0];
  }
}

// ---------------------------------------------------------------------------
// lc2: h2[32][4096] = relu(conv3x3(h1)), halo staged from global.
// ocg==0 blocks also compute per-pixel LN1 stats of x (mu1, rs1).
__global__ __launch_bounds__(256) void lc2_kernel(
    const float* __restrict__ h1, const float* __restrict__ w2,
    const float* __restrict__ b2, const float* __restrict__ x,
    float* __restrict__ h2, float* __restrict__ mu1, float* __restrict__ rs1) {
  __shared__ float tin[32][324];  // 18x18 halo per ic
  __shared__ float swt[4][32][9];
  int tile = blockIdx.x, ocg = blockIdx.y;
  int ty0 = (tile >> 2) * 16, tx0 = (tile & 3) * 16;
  int tid = threadIdx.x;
  for (int idx = tid; idx < 32 * 324; idx += 256) {
    int ic = idx / 324, pos = idx - ic * 324;
    int py = pos / 18, px = pos - py * 18;
    int gy = ty0 + py - 1, gx = tx0 + px - 1;
    tin[ic][pos] = (gy >= 0 && gy < IMG && gx >= 0 && gx < IMG)
                       ? h1[ic * NPIX + gy * IMG + gx]
                       : 0.f;
  }
  for (int idx = tid; idx < 4 * 32 * 9; idx += 256) {
    int o = idx / 288, r = idx - o * 288;
    swt[o][r / 9][r % 9] = w2[(ocg * 4 + o) * 288 + r];
  }
  __syncthreads();
  int ly = tid >> 4, lx = tid & 15;
  int p = (ty0 + ly) * IMG + tx0 + lx;
  float acc[4];
#pragma unroll
  for (int o = 0; o < 4; o++) acc[o] = b2[ocg * 4 + o];
  for (int ic = 0; ic < 32; ic++) {
    float v[9];
#pragma unroll
    for (int dy = 0; dy < 3; dy++)
#pragma unroll
      for (int dx = 0; dx < 3; dx++)
        v[dy * 3 + dx] = tin[ic][(ly + dy) * 18 + lx + dx];
#pragma unroll
    for (int o = 0; o < 4; o++)
#pragma unroll
      for (int t = 0; t < 9; t++) acc[o] = fmaf(swt[o][ic][t], v[t], acc[o]);
  }
#pragma unroll
  for (int o = 0; o < 4; o++)
    h2[(ocg * 4 + o) * NPIX + p] = fmaxf(acc[o], 0.f);
  if (ocg == 0) {
    float s = 0.f, q = 0.f;
#pragma unroll 8
    for (int cc = 0; cc < 64; cc++) {
      float xv = x[cc * NPIX + p];
      s += xv;
      q = fmaf(xv, xv, q);
    }
    float mu = s * (1.f / 64.f);
    mu1[p] = mu;
    rs1[p] = rsqrtf(q * (1.f / 64.f) - mu * mu + 1e-5f);
  }
}

// ---------------------------------------------------------------------------
// Fused per-pixel LayerNorm (precomputed stats) + qkv 1x1 GEMM + (gam/bet
// GEMMs in-register) + modulation + hi/lo split store. grid (64, 3).
__global__ __launch_bounds__(256) void ln_qkv_kernel(
    const float* __restrict__ X, const float* __restrict__ mu1,
    const float* __restrict__ rs1, const float* __restrict__ lnw,
    const float* __restrict__ lnb, const float* __restrict__ W,
    const float* __restrict__ bias, const float* __restrict__ gamW,
    const float* __restrict__ gamB, const float* __restrict__ betW,
    const float* __restrict__ betB, const float* __restrict__ h2,
    const float* __restrict__ pooled, const float* __restrict__ bsums,
    const float* __restrict__ alpha, unsigned short* __restrict__ qhl,
    unsigned short* __restrict__ khl, unsigned short* __restrict__ vthx,
    unsigned short* __restrict__ vtlx) {
  const float QSCALE = 0.35355339059327376f * 1.4426950408889634f;
  __shared__ float xs[64][64];
  __shared__ float wsh[64][64];
  __shared__ float h2s[32][64];
  __shared__ float wgs[32][64];
  __shared__ float wbs[32][64];
  __shared__ float mu[64];
  __shared__ float rs[64];
  int n0 = blockIdx.x * 64, part = blockIdx.y, m0 = part * 64;
  int tid = threadIdx.x;
  int c = tid >> 2, pg = (tid & 3) * 16;
  if (tid < 64) {
    mu[tid] = mu1[n0 + tid];
    rs[tid] = rs1[n0 + tid];
  }
  {
    const float4* src = (const float4*)&X[c * NPIX + n0 + pg];
    float4* dst = (float4*)&xs[c][pg];
    dst[0] = src[0]; dst[1] = src[1]; dst[2] = src[2]; dst[3] = src[3];
  }
  {
    int m = tid >> 2, kg = (tid & 3) * 16;
    const float4* wr = (const float4*)&W[(m0 + m) * 64 + kg];
    float4 w0 = wr[0], w1 = wr[1], w2 = wr[2], w3 = wr[3];
    float wv[16] = {w0.x, w0.y, w0.z, w0.w, w1.x, w1.y, w1.z, w1.w,
                    w2.x, w2.y, w2.z, w2.w, w3.x, w3.y, w3.z, w3.w};
#pragma unroll
    for (int j = 0; j < 16; j++) wsh[kg + j][m] = wv[j];
  }
  {
    int i0 = tid * 2;
    int k = i0 >> 4, nf = (i0 & 15) * 4;
    *(float4*)&h2s[k][nf] = *(const float4*)&h2[k * NPIX + n0 + nf];
    int i1 = i0 + 1;
    int k1 = i1 >> 4, nf1 = (i1 & 15) * 4;
    *(float4*)&h2s[k1][nf1] = *(const float4*)&h2[k1 * NPIX + n0 + nf1];
  }
  {
    int m = tid >> 2, kg = (tid & 3) * 8;
    const float4* g0 = (const float4*)&gamW[m * 32 + kg];
    float4 a = g0[0], b4 = g0[1];
    float gv[8] = {a.x, a.y, a.z, a.w, b4.x, b4.y, b4.z, b4.w};
#pragma unroll
    for (int j = 0; j < 8; j++) wgs[kg + j][m] = gv[j];
    const float4* bb0 = (const float4*)&betW[m * 32 + kg];
    float4 c4 = bb0[0], d4 = bb0[1];
    float bv[8] = {c4.x, c4.y, c4.z, c4.w, d4.x, d4.y, d4.z, d4.w};
#pragma unroll
    for (int j = 0; j < 8; j++) wbs[kg + j][m] = bv[j];
  }
  __syncthreads();
  {
    float wc = lnw[c], bc = lnb[c];
#pragma unroll
    for (int j = 0; j < 16; j++) {
      int p = pg + j;
      xs[c][p] = (xs[c][p] - mu[p]) * rs[p] * wc + bc;
    }
  }
  __syncthreads();
  int tx = tid & 15, ty = tid >> 4;
  float ga[4][4] = {}, ba[4][4] = {};
#pragma unroll 8
  for (int kk = 0; kk < 32; kk++) {
    float4 wg4 = *(const float4*)&wgs[kk][ty * 4];
    float4 wb4 = *(const float4*)&wbs[kk][ty * 4];
    float4 h24 = *(const float4*)&h2s[kk][tx * 4];
    float gv[4] = {wg4.x, wg4.y, wg4.z, wg4.w};
    float bv[4] = {wb4.x, wb4.y, wb4.z, wb4.w};
    float hv[4] = {h24.x, h24.y, h24.z, h24.w};
#pragma unroll
    for (int im = 0; im < 4; im++)
#pragma unroll
      for (int in = 0; in < 4; in++) {
        ga[im][in] = fmaf(gv[im], hv[in], ga[im][in]);
        ba[im][in] = fmaf(bv[im], hv[in], ba[im][in]);
      }
  }
#pragma unroll
  for (int im = 0; im < 4; im++) {
    int cc = ty * 4 + im;
    float gb = gamB[cc], bb2 = betB[cc];
#pragma unroll
    for (int in = 0; in < 4; in++) {
      ga[im][in] += gb;
      ba[im][in] += bb2;
    }
  }
  float acc[4][4] = {};
#pragma unroll 8
  for (int kk = 0; kk < 64; kk++) {
    float4 a = *(const float4*)&wsh[kk][ty * 4];
    float4 b4 = *(const float4*)&xs[kk][tx * 4];
    float av[4] = {a.x, a.y, a.z, a.w};
    float bv[4] = {b4.x, b4.y, b4.z, b4.w};
#pragma unroll
    for (int im = 0; im < 4; im++)
#pragma unroll
      for (int in = 0; in < 4; in++)
        acc[im][in] = fmaf(av[im], bv[in], acc[im][in]);
  }
  float val[4][4];
#pragma unroll
  for (int im = 0; im < 4; im++) {
    int cc = ty * 4 + im;
    float bv = bias[m0 + cc];
#pragma unroll
    for (int in = 0; in < 4; in++)
      val[im][in] = fmaf(ga[im][in], acc[im][in] + bv, ba[im][in]);
  }
  if (part == 0) {
    float msum = 0.f;
#pragma unroll
    for (int t = 0; t < 16; t++) msum += bsums[t];
    float mean = msum * (1.f / 4096.f);
    float a0 = alpha[0];
    const float4 pv = *(const float4*)&pooled[n0 + tx * 4];
    float iv[4] = {a0 * (pv.x - mean), a0 * (pv.y - mean),
                   a0 * (pv.z - mean), a0 * (pv.w - mean)};
#pragma unroll
    for (int im = 0; im < 4; im++)
#pragma unroll
      for (int in = 0; in < 4; in++)
        val[im][in] = (val[im][in] + iv[in]) * QSCALE;
  }
  if (part < 2) {
    unsigned short* dst = (part == 0) ? qhl : khl;
    int h = ty >> 1, d0 = (ty & 1) * 4;
#pragma unroll
    for (int in = 0; in < 4; in++) {
      int n = n0 + tx * 4 + in;
      unsigned int pk[4];
#pragma unroll
      for (int im = 0; im < 4; im++) pk[im] = split_pack(val[im][in]);
      short4 hi, lo;
      hi.x = (short)(pk[0] & 0xffffu); hi.y = (short)(pk[1] & 0xffffu);
      hi.z = (short)(pk[2] & 0xffffu); hi.w = (short)(pk[3] & 0xffffu);
      lo.x = (short)(pk[0] >> 16); lo.y = (short)(pk[1] >> 16);
      lo.z = (short)(pk[2] >> 16); lo.w = (short)(pk[3] >> 16);
      unsigned short* base = dst + ((size_t)(h * NPIX + n) << 4) + d0;
      *(short4*)base = hi;
      *(short4*)(base + 8) = lo;
    }
  } else {
    int nq = n0 + tx * 4;
    int off0 = (nq >> 5) * 32 + ((nq >> 4) & 1) * 4 + ((nq >> 2) & 3) * 8;
#pragma unroll
    for (int im = 0; im < 4; im++) {
      int cc = ty * 4 + im;
      unsigned int pk[4];
#pragma unroll
      for (int in = 0; in < 4; in++) pk[in] = split_pack(val[im][in]);
      short4 hi, lo;
      hi.x = (short)(pk[0] & 0xffffu); hi.y = (short)(pk[1] & 0xffffu);
      hi.z = (short)(pk[2] & 0xffffu); hi.w = (short)(pk[3] & 0xffffu);
      lo.x = (short)(pk[0] >> 16); lo.y = (short)(pk[1] >> 16);
      lo.z = (short)(pk[2] >> 16); lo.w = (short)(pk[3] >> 16);
      *(short4*)(vthx + (size_t)cc * NPIX + off0) = hi;
      *(short4*)(vtlx + (size_t)cc * NPIX + off0) = lo;
    }
  }
}

// ---------------------------------------------------------------------------
// MFMA flash attention, r8-proven config: JP=4 (1024-j slices), 2 i-tiles
// per wave, zero LDS, no online max. grid (32 i-tiles of 128, 8 heads, 4 jp).
__global__ __launch_bounds__(256, 4) void attn_kernel(
    const unsigned short* __restrict__ qhl,
    const unsigned short* __restrict__ khl,
    const unsigned short* __restrict__ vthx,
    const unsigned short* __restrict__ vtlx,
    const unsigned short* __restrict__ cbuf, float* __restrict__ pacc,
    float* __restrict__ pl) {
  int tid = threadIdx.x;
  int wave = tid >> 6, lane = tid & 63;
  int g = lane >> 4, c = lane & 15;
  int h = blockIdx.y, jp = blockIdx.z;
  int i0 = blockIdx.x * 128 + wave * 32;
  int jbase = jp * 1024;
  const bf16x8 qB0 = *(const bf16x8*)(qhl + ((size_t)(h * NPIX + i0 + c) << 4) +
                                      ((g & 1) << 3));
  const bf16x8 qB1 = *(const bf16x8*)(
      qhl + ((size_t)(h * NPIX + i0 + 16 + c) << 4) + ((g & 1) << 3));
  const unsigned short* kp =
      khl + ((size_t)(h * NPIX + jbase + c) << 4) + ((g >> 1) << 3);
  const unsigned short* vhp;
  const unsigned short* vlp;
  int vstep;
  if (c < 8) {
    vhp = vthx + (size_t)(h * 8 + c) * NPIX + jbase + (g << 3);
    vlp = vtlx + (size_t)(h * 8 + c) * NPIX + jbase + (g << 3);
    vstep = 32;
  } else {
    vhp = (c == 8) ? cbuf : (cbuf + 8);  // ones row / zero rows
    vlp = cbuf + 8;
    vstep = 0;
  }
  floatx4 zero4 = {0.f, 0.f, 0.f, 0.f};
  floatx4 aH0 = zero4, aM0 = zero4, aH1 = zero4, aM1 = zero4;
#pragma unroll 2
  for (int jt = 0; jt < 32; ++jt) {
    bf16x8 ka0 = *(const bf16x8*)kp;
    bf16x8 ka1 = *(const bf16x8*)(kp + 256);
    bf16x8 avh = *(const bf16x8*)vhp;
    bf16x8 avl = *(const bf16x8*)vlp;
    kp += 512;
    vhp += vstep;
    vlp += vstep;
    floatx4 s00 =
        __builtin_amdgcn_mfma_f32_16x16x32_bf16(ka0, qB0, zero4, 0, 0, 0);
    floatx4 s01 =
        __builtin_amdgcn_mfma_f32_16x16x32_bf16(ka1, qB0, zero4, 0, 0, 0);
    floatx4 s10 =
        __builtin_amdgcn_mfma_f32_16x16x32_bf16(ka0, qB1, zero4, 0, 0, 0);
    floatx4 s11 =
        __builtin_amdgcn_mfma_f32_16x16x32_bf16(ka1, qB1, zero4, 0, 0, 0);
    {
      float p0 = __builtin_amdgcn_exp2f(fminf(s00[0], 80.f));
      float p1 = __builtin_amdgcn_exp2f(fminf(s00[1], 80.f));
      float p2 = __builtin_amdgcn_exp2f(fminf(s00[2], 80.f));
      float p3 = __builtin_amdgcn_exp2f(fminf(s00[3], 80.f));
      float p4 = __builtin_amdgcn_exp2f(fminf(s01[0], 80.f));
      float p5 = __builtin_amdgcn_exp2f(fminf(s01[1], 80.f));
      float p6 = __builtin_amdgcn_exp2f(fminf(s01[2], 80.f));
      float p7 = __builtin_amdgcn_exp2f(fminf(s01[3], 80.f));
      uintx4 bh;
      bh.x = hi_pair(p0, p1);
      bh.y = hi_pair(p2, p3);
      bh.z = hi_pair(p4, p5);
      bh.w = hi_pair(p6, p7);
      bf16x8 pbh = __builtin_bit_cast(bf16x8, bh);
      aH0 = __builtin_amdgcn_mfma_f32_16x16x32_bf16(avh, pbh, aH0, 0, 0, 0);
      aM0 = __builtin_amdgcn_mfma_f32_16x16x32_bf16(avl, pbh, aM0, 0, 0, 0);
    }
    {
      float p0 = __builtin_amdgcn_exp2f(fminf(s10[0], 80.f));
      float p1 = __builtin_amdgcn_exp2f(fminf(s10[1], 80.f));
      float p2 = __builtin_amdgcn_exp2f(fminf(s10[2], 80.f));
      float p3 = __builtin_amdgcn_exp2f(fminf(s10[3], 80.f));
      float p4 = __builtin_amdgcn_exp2f(fminf(s11[0], 80.f));
      float p5 = __builtin_amdgcn_exp2f(fminf(s11[1], 80.f));
      float p6 = __builtin_amdgcn_exp2f(fminf(s11[2], 80.f));
      float p7 = __builtin_amdgcn_exp2f(fminf(s11[3], 80.f));
      uintx4 bh;
      bh.x = hi_pair(p0, p1);
      bh.y = hi_pair(p2, p3);
      bh.z = hi_pair(p4, p5);
      bh.w = hi_pair(p6, p7);
      bf16x8 pbh = __builtin_bit_cast(bf16x8, bh);
      aH1 = __builtin_amdgcn_mfma_f32_16x16x32_bf16(avh, pbh, aH1, 0, 0, 0);
      aM1 = __builtin_amdgcn_mfma_f32_16x16x32_bf16(avl, pbh, aM1, 0, 0, 0);
    }
  }
  floatx4 o0 = aH0 + aM0;
  floatx4 o1 = aH1 + aM1;
  if (g < 2) {
    size_t b0 = (size_t)((jp * 8 + h) * NPIX + i0 + c);
    *(float4*)&pacc[b0 * 8 + g * 4] = make_float4(o0[0], o0[1], o0[2], o0[3]);
    size_t b1 = b0 + 16;
    *(float4*)&pacc[b1 * 8 + g * 4] = make_float4(o1[0], o1[1], o1[2], o1[3]);
  } else if (g == 2) {
    pl[(size_t)((jp * 8 + h) * NPIX + i0 + c)] = o0[0];
    pl[(size_t)((jp * 8 + h) * NPIX + i0 + 16 + c)] = o1[0];
  }
}

// ---------------------------------------------------------------------------
// Fused: combine 4 j-partitions -> proj GEMM + residual -> x1 (ch==0) + LN2
// stats -> LN -> one 64-ch slice of ffn1 -> f1. grid (128, 4).
__global__ __launch_bounds__(256) void proj_ffn1_kernel(
    const float* __restrict__ pacc, const float* __restrict__ pl,
    const float* __restrict__ Wp, const float* __restrict__ bp,
    const float* __restrict__ x, const float* __restrict__ ln2w,
    const float* __restrict__ ln2b, const float* __restrict__ W1,
    const float* __restrict__ b1f, float* __restrict__ x1,
    float* __restrict__ f1) {
  __shared__ float at[64][33];
  __shared__ float wsh[64][64];
  __shared__ float xsl[64][33];
  __shared__ float ps[8][33];
  __shared__ float pq[8][33];
  __shared__ float mus[32];
  __shared__ float rss[32];
  int n0 = blockIdx.x * 32;
  int ch = blockIdx.y;
  int tid = threadIdx.x;
  {
    int mm = tid >> 2, kg = (tid & 3) * 16;
    const float4* wr = (const float4*)&Wp[mm * 64 + kg];
    float4 w0 = wr[0], w1 = wr[1], w2 = wr[2], w3 = wr[3];
    float wv[16] = {w0.x, w0.y, w0.z, w0.w, w1.x, w1.y, w1.z, w1.w,
                    w2.x, w2.y, w2.z, w2.w, w3.x, w3.y, w3.z, w3.w};
#pragma unroll
    for (int j = 0; j < 16; j++) wsh[kg + j][mm] = wv[j];
  }
  {
    int hh = tid >> 5, nn = tid & 31;
    int i = n0 + nn;
    float L = 0.f, o[8] = {};
#pragma unroll
    for (int p = 0; p < 4; p++) {
      size_t base = (size_t)((p * 8 + hh) * NPIX + i);
      L += pl[base];
      const float4 a0 = *(const float4*)&pacc[base * 8];
      const float4 a1 = *(const float4*)&pacc[base * 8 + 4];
      o[0] += a0.x; o[1] += a0.y; o[2] += a0.z; o[3] += a0.w;
      o[4] += a1.x; o[5] += a1.y; o[6] += a1.z; o[7] += a1.w;
    }
    float inv = 1.f / L;
#pragma unroll
    for (int d = 0; d < 8; d++) at[hh * 8 + d][nn] = o[d] * inv;
  }
  __syncthreads();
  int ty = tid >> 5, tx = tid & 31;
  float acc[8] = {};
#pragma unroll 8
  for (int k = 0; k < 64; k++) {
    float b = at[k][tx];
    float4 a0 = *(const float4*)&wsh[k][ty * 8];
    float4 a1 = *(const float4*)&wsh[k][ty * 8 + 4];
    acc[0] = fmaf(a0.x, b, acc[0]);
    acc[1] = fmaf(a0.y, b, acc[1]);
    acc[2] = fmaf(a0.z, b, acc[2]);
    acc[3] = fmaf(a0.w, b, acc[3]);
    acc[4] = fmaf(a1.x, b, acc[4]);
    acc[5] = fmaf(a1.y, b, acc[5]);
    acc[6] = fmaf(a1.z, b, acc[6]);
    acc[7] = fmaf(a1.w, b, acc[7]);
  }
  float v[8], sn = 0.f, qn = 0.f;
#pragma unroll
  for (int im = 0; im < 8; im++) {
    int row = ty * 8 + im;
    float vv = acc[im] + bp[row] + x[row * NPIX + n0 + tx];
    v[im] = vv;
    sn += vv;
    qn = fmaf(vv, vv, qn);
  }
  if (ch == 0) {
#pragma unroll
    for (int im = 0; im < 8; im++)
      x1[(ty * 8 + im) * NPIX + n0 + tx] = v[im];
  }
  ps[ty][tx] = sn;
  pq[ty][tx] = qn;
  __syncthreads();
  if (tid < 32) {
    float s = 0.f, q = 0.f;
#pragma unroll
    for (int t = 0; t < 8; t++) {
      s += ps[t][tid];
      q += pq[t][tid];
    }
    float mu = s * (1.f / 64.f);
    mus[tid] = mu;
    rss[tid] = rsqrtf(q * (1.f / 64.f) - mu * mu + 1e-5f);
  }
  __syncthreads();
  {
    float muv = mus[tx], rsv = rss[tx];
#pragma unroll
    for (int im = 0; im < 8; im++) {
      int row = ty * 8 + im;
      xsl[row][tx] = (v[im] - muv) * rsv * ln2w[row] + ln2b[row];
    }
  }
  {
    int mm = tid >> 2, kg = (tid & 3) * 16;
    const float4* wr = (const float4*)&W1[(ch * 64 + mm) * 64 + kg];
    float4 w0 = wr[0], w1 = wr[1], w2 = wr[2], w3 = wr[3];
    float wv[16] = {w0.x, w0.y, w0.z, w0.w, w1.x, w1.y, w1.z, w1.w,
                    w2.x, w2.y, w2.z, w2.w, w3.x, w3.y, w3.z, w3.w};
#pragma unroll
    for (int j = 0; j < 16; j++) wsh[kg + j][mm] = wv[j];
  }
  __syncthreads();
  float a2[8] = {};
#pragma unroll 8
  for (int k = 0; k < 64; k++) {
    float b = xsl[k][tx];
    float4 a0 = *(const float4*)&wsh[k][ty * 8];
    float4 a1 = *(const float4*)&wsh[k][ty * 8 + 4];
    a2[0] = fmaf(a0.x, b, a2[0]);
    a2[1] = fmaf(a0.y, b, a2[1]);
    a2[2] = fmaf(a0.z, b, a2[2]);
    a2[3] = fmaf(a0.w, b, a2[3]);
    a2[4] = fmaf(a1.x, b, a2[4]);
    a2[5] = fmaf(a1.y, b, a2[5]);
    a2[6] = fmaf(a1.z, b, a2[6]);
    a2[7] = fmaf(a1.w, b, a2[7]);
  }
#pragma unroll
  for (int im = 0; im < 8; im++) {
    int row = ch * 64 + ty * 8 + im;
    f1[row * NPIX + n0 + tx] = a2[im] + b1f[row];
  }
}

// ---------------------------------------------------------------------------
// Depthwise 3x3 + exact GELU; 4 horizontal px/thread (unchanged).
__global__ __launch_bounds__(256) void dw_gelu_kernel(
    const float* __restrict__ f1, const float* __restrict__ w,
    const float* __restrict__ b, float* __restrict__ f2) {
  int t = blockIdx.x * 256 + threadIdx.x;
  int c = t >> 10, pq = t & 1023;
  int py = pq >> 4, px0 = (pq & 15) << 2;
  const float* base = f1 + c * NPIX;
  float wv[9];
#pragma unroll
  for (int i = 0; i < 9; i++) wv[i] = w[c * 9 + i];
  float bc = b[c];
  float a[4] = {bc, bc, bc, bc};
#pragma unroll
  for (int dy = 0; dy < 3; dy++) {
    int y = py + dy - 1;
    if (y < 0 || y > 63) continue;
    const float* row = base + y * IMG + px0;
    float4 mid = *(const float4*)row;
    float left = (px0 > 0) ? row[-1] : 0.f;
    float right = (px0 < 60) ? row[4] : 0.f;
    float win[6] = {left, mid.x, mid.y, mid.z, mid.w, right};
#pragma unroll
    for (int o = 0; o < 4; o++)
#pragma unroll
      for (int dx = 0; dx < 3; dx++)
        a[o] = fmaf(wv[dy * 3 + dx], win[o + dx], a[o]);
  }
  float4 o4;
  float* op = &o4.x;
#pragma unroll
  for (int o = 0; o < 4; o++)
    op[o] = 0.5f * a[o] * (1.f + erff(a[o] * 0.70710678118654752f));
  *(float4*)&f2[c * NPIX + py * IMG + px0] = o4;
}

// ---------------------------------------------------------------------------
// ffn2 GEMM, single-barrier full-K staging: out = W[64][256]*f2 + bias + x1.
// LDS: xs[256][32] (32 KB) + wsh[256][16] (16 KB) -> 3 blocks/CU.
// grid (128 n-tiles of 32, 4 m-tiles of 16). xs/wsh reads broadcast.
__global__ __launch_bounds__(256) void ffn2_kernel(
    const float* __restrict__ W, const float* __restrict__ X,
    const float* __restrict__ bias, const float* __restrict__ resid,
    float* __restrict__ C) {
  __shared__ float xs[256][32];
  __shared__ float wsh[256][16];
  int n0 = blockIdx.x * 32, m0 = blockIdx.y * 16;
  int tid = threadIdx.x;
  // stage X: 2048 float4, 8 per thread (coalesced within rows)
#pragma unroll
  for (int e = tid; e < 2048; e += 256) {
    int k = e >> 3, nf = (e & 7) * 4;
    *(float4*)&xs[k][nf] = *(const float4*)&X[k * NPIX + n0 + nf];
  }
  // stage W: 4096 scalars, 16 per thread (coalesced reads along k)
#pragma unroll
  for (int e = tid; e < 4096; e += 256) {
    int mm = e >> 8, kk = e & 255;
    wsh[kk][mm] = W[(m0 + mm) * 256 + kk];
  }
  __syncthreads();
  int m = tid >> 4, np = (tid & 15) * 2;
  float acc0 = 0.f, acc1 = 0.f;
#pragma unroll 8
  for (int kk = 0; kk < 256; kk++) {
    float a = wsh[kk][m];
    float2 b2 = *(const float2*)&xs[kk][np];
    acc0 = fmaf(a, b2.x, acc0);
    acc1 = fmaf(a, b2.y, acc1);
  }
  int row = m0 + m;
  float bv = bias[row];
  const float2 r2 = *(const float2*)&resid[row * NPIX + n0 + np];
  float2 o = make_float2(acc0 + bv + r2.x, acc1 + bv + r2.y);
  *(float2*)&C[row * NPIX + n0 + np] = o;
}

// ---------------------------------------------------------------------------
extern "C" void kernel_launch(void* const* d_in, const int* in_sizes, int n_in,
                              void* d_out, int out_size, void* d_ws,
                              size_t ws_size, hipStream_t stream) {
  const float* x      = (const float*)d_in[0];
  const float* luma   = (const float*)d_in[1];
  const float* ln1_w  = (const float*)d_in[2];
  const float* ln1_b  = (const float*)d_in[3];
  const float* qkv_w  = (const float*)d_in[4];
  const float* qkv_b  = (const float*)d_in[5];
  const float* proj_w = (const float*)d_in[6];
  const float* proj_b = (const float*)d_in[7];
  const float* lc1_w  = (const float*)d_in[8];
  const float* lc1_b  = (const float*)d_in[9];
  const float* lc2_w  = (const float*)d_in[10];
  const float* lc2_b  = (const float*)d_in[11];
  const float* gam_w  = (const float*)d_in[12];
  const float* gam_b  = (const float*)d_in[13];
  const float* bet_w  = (const float*)d_in[14];
  const float* bet_b  = (const float*)d_in[15];
  const float* alpha  = (const float*)d_in[16];
  const float* ln2_w  = (const float*)d_in[17];
  const float* ln2_b  = (const float*)d_in[18];
  const float* ffn1_w = (const float*)d_in[19];
  const float* ffn1_b = (const float*)d_in[20];
  const float* dw_w   = (const float*)d_in[21];
  const float* dw_b   = (const float*)d_in[22];
  const float* ffn2_w = (const float*)d_in[23];
  const float* ffn2_b = (const float*)d_in[24];
  float* out = (float*)d_out;

  float* w = (float*)d_ws;
  float* pooled = w + 0;        // 4096
  float* bsums  = w + 4096;     // 64 (16 used)
  unsigned short* cbuf = (unsigned short*)(w + 4160);     // 64 f (16 us used)
  float* mu1 = w + 4224;        // 4096
  float* rs1 = w + 8320;        // 4096
  unsigned short* qhl  = (unsigned short*)(w + 12416);    // 262144 f
  unsigned short* khl  = (unsigned short*)(w + 274560);   // 262144 f
  unsigned short* vthx = (unsigned short*)(w + 536704);   // 131072 f
  unsigned short* vtlx = (unsigned short*)(w + 667776);   // 131072 f
  float* pacc = w + 798848;    // 1048576 (JP=4)
  float* pl   = w + 1847424;   // 131072
  float* x1   = w + 1978496;   // 262144
  float* f1   = w + 2240640;   // 1048576
  float* f2   = w + 3289216;   // 1048576
  float* h2   = w + 4337792;   // 131072
  float* h1   = w + 4468864;   // 131072

  lc1_kernel<<<dim3(16, 8), 256, 0, stream>>>(luma, lc1_w, lc1_b, h1, pooled,
                                              bsums, cbuf);
  lc2_kernel<<<dim3(16, 8), 256, 0, stream>>>(h1, lc2_w, lc2_b, x, h2, mu1,
                                              rs1);
  ln_qkv_kernel<<<dim3(64, 3), 256, 0, stream>>>(
      x, mu1, rs1, ln1_w, ln1_b, qkv_w, qkv_b, gam_w, gam_b, bet_w, bet_b, h2,
      pooled, bsums, alpha, qhl, khl, vthx, vtlx);
  attn_kernel<<<dim3(32, 8, 4), 256, 0, stream>>>(qhl, khl, vthx, vtlx, cbuf,
                                                  pacc, pl);
  proj_ffn1_kernel<<<dim3(128, 4), 256, 0, stream>>>(
      pacc, pl, proj_w, proj_b, x, ln2_w, ln2_b, ffn1_w, ffn1_b, x1, f1);
  dw_gelu_kernel<<<1024, 256, 0, stream>>>(f1, dw_w, dw_b, f2);
  ffn2_kernel<<<dim3(128, 4), 256, 0, stream>>>(ffn2_w, f2, ffn2_b, x1, out);
}

// Round 11
// 202.478 us; speedup vs baseline: 1.0168x; 1.0006x over previous
//
#include <hip/hip_runtime.h>
#include <math.h>

// B=1, C=64, H=W=64, N=4096, heads=8, dh=8, inner=64, hid_lc=32, hid_f=256.
#define NPIX 4096
#define IMG 64

typedef __attribute__((ext_vector_type(8))) short bf16x8;
typedef __attribute__((ext_vector_type(4))) float floatx4;
typedef __attribute__((ext_vector_type(4))) unsigned int uintx4;

// fp32 -> (hi bf16 in low16) | (lo bf16 in high16), lo = x - f32(hi)
__device__ __forceinline__ unsigned int split_pack(float x) {
  unsigned int u = __float_as_uint(x);
  unsigned int hif = u & 0xffff0000u;
  float lof = x - __uint_as_float(hif);
  return (u >> 16) | (__float_as_uint(lof) & 0xffff0000u);
}

// pack hi16 of two floats: low16 = hi16(a), high16 = hi16(b)
__device__ __forceinline__ unsigned int hi_pair(float a, float b) {
  return (__float_as_uint(a) >> 16) | (__float_as_uint(b) & 0xffff0000u);
}

// ---------------------------------------------------------------------------
// lc1: h1[32][4096] = relu(conv3x3(luma)), thread = 1 px x 4 oc.
__global__ __launch_bounds__(256) void lc1_kernel(
    const float* __restrict__ luma, const float* __restrict__ w1,
    const float* __restrict__ b1, float* __restrict__ h1,
    float* __restrict__ pooled, float* __restrict__ bsums,
    unsigned short* __restrict__ cbuf) {
  __shared__ float red[256];
  int tile = blockIdx.x, ocg = blockIdx.y;
  int tid = threadIdx.x;
  if (tile == 0 && ocg == 0 && tid < 16) cbuf[tid] = (tid < 8) ? 0x3F80 : 0;
  int p = tile * 256 + tid;
  int py = p >> 6, px = p & 63;
  float v[9];
#pragma unroll
  for (int dy = 0; dy < 3; dy++)
#pragma unroll
    for (int dx = 0; dx < 3; dx++) {
      int y = py + dy - 1, x = px + dx - 1;
      v[dy * 3 + dx] =
          (y >= 0 && y < IMG && x >= 0 && x < IMG) ? luma[y * IMG + x] : 0.f;
    }
#pragma unroll
  for (int o = 0; o < 4; o++) {
    int oc = ocg * 4 + o;
    float s = b1[oc];
#pragma unroll
    for (int t = 0; t < 9; t++) s = fmaf(w1[oc * 9 + t], v[t], s);
    h1[oc * NPIX + p] = fmaxf(s, 0.f);
  }
  if (ocg == 0) {
    float sv = 0.f;
#pragma unroll
    for (int t = 0; t < 9; t++) sv += v[t];
    float cy = 3.f - (py == 0 ? 1.f : 0.f) - (py == 63 ? 1.f : 0.f);
    float cx = 3.f - (px == 0 ? 1.f : 0.f) - (px == 63 ? 1.f : 0.f);
    float pv = (cy * cx - sv) * (1.f / 9.f);
    pooled[p] = pv;
    red[tid] = pv;
    __syncthreads();
    for (int st = 128; st > 0; st >>= 1) {
      if (tid < st) red[tid] += red[tid + st];
      __syncthreads();
    }
    if (tid == 0) bsums[tile] = red[0];
  }
}

// ---------------------------------------------------------------------------
// lc2: h2[32][4096] = relu(conv3x3(h1)), halo staged from global.
// ocg==0 blocks also compute per-pixel LN1 stats of x (mu1, rs1).
__global__ __launch_bounds__(256) void lc2_kernel(
    const float* __restrict__ h1, const float* __restrict__ w2,
    const float* __restrict__ b2, const float* __restrict__ x,
    float* __restrict__ h2, float* __restrict__ mu1, float* __restrict__ rs1) {
  __shared__ float tin[32][324];  // 18x18 halo per ic
  __shared__ float swt[4][32][9];
  int tile = blockIdx.x, ocg = blockIdx.y;
  int ty0 = (tile >> 2) * 16, tx0 = (tile & 3) * 16;
  int tid = threadIdx.x;
  for (int idx = tid; idx < 32 * 324; idx += 256) {
    int ic = idx / 324, pos = idx - ic * 324;
    int py = pos / 18, px = pos - py * 18;
    int gy = ty0 + py - 1, gx = tx0 + px - 1;
    tin[ic][pos] = (gy >= 0 && gy < IMG && gx >= 0 && gx < IMG)
                       ? h1[ic * NPIX + gy * IMG + gx]
                       : 0.f;
  }
  for (int idx = tid; idx < 4 * 32 * 9; idx += 256) {
    int o = idx / 288, r = idx - o * 288;
    swt[o][r / 9][r % 9] = w2[(ocg * 4 + o) * 288 + r];
  }
  __syncthreads();
  int ly = tid >> 4, lx = tid & 15;
  int p = (ty0 + ly) * IMG + tx0 + lx;
  float acc[4];
#pragma unroll
  for (int o = 0; o < 4; o++) acc[o] = b2[ocg * 4 + o];
  for (int ic = 0; ic < 32; ic++) {
    float v[9];
#pragma unroll
    for (int dy = 0; dy < 3; dy++)
#pragma unroll
      for (int dx = 0; dx < 3; dx++)
        v[dy * 3 + dx] = tin[ic][(ly + dy) * 18 + lx + dx];
#pragma unroll
    for (int o = 0; o < 4; o++)
#pragma unroll
      for (int t = 0; t < 9; t++) acc[o] = fmaf(swt[o][ic][t], v[t], acc[o]);
  }
#pragma unroll
  for (int o = 0; o < 4; o++)
    h2[(ocg * 4 + o) * NPIX + p] = fmaxf(acc[o], 0.f);
  if (ocg == 0) {
    float s = 0.f, q = 0.f;
#pragma unroll 8
    for (int cc = 0; cc < 64; cc++) {
      float xv = x[cc * NPIX + p];
      s += xv;
      q = fmaf(xv, xv, q);
    }
    float mu = s * (1.f / 64.f);
    mu1[p] = mu;
    rs1[p] = rsqrtf(q * (1.f / 64.f) - mu * mu + 1e-5f);
  }
}

// ---------------------------------------------------------------------------
// Fused per-pixel LayerNorm (precomputed stats) + qkv 1x1 GEMM + (gam/bet
// GEMMs in-register) + modulation + hi/lo split store.
// 32-px n-tiles for occupancy: grid (128, 3). Thread = 4 ch x 2 px.
__global__ __launch_bounds__(256) void ln_qkv_kernel(
    const float* __restrict__ X, const float* __restrict__ mu1,
    const float* __restrict__ rs1, const float* __restrict__ lnw,
    const float* __restrict__ lnb, const float* __restrict__ W,
    const float* __restrict__ bias, const float* __restrict__ gamW,
    const float* __restrict__ gamB, const float* __restrict__ betW,
    const float* __restrict__ betB, const float* __restrict__ h2,
    const float* __restrict__ pooled, const float* __restrict__ bsums,
    const float* __restrict__ alpha, unsigned short* __restrict__ qhl,
    unsigned short* __restrict__ khl, unsigned short* __restrict__ vthx,
    unsigned short* __restrict__ vtlx) {
  const float QSCALE = 0.35355339059327376f * 1.4426950408889634f;
  __shared__ float xs[64][32];
  __shared__ float wsh[64][64];
  __shared__ float h2s[32][32];
  __shared__ float wgs[32][64];
  __shared__ float wbs[32][64];
  __shared__ float mu[32];
  __shared__ float rs[32];
  int n0 = blockIdx.x * 32, part = blockIdx.y, m0 = part * 64;
  int tid = threadIdx.x;
  if (tid < 32) {
    mu[tid] = mu1[n0 + tid];
    rs[tid] = rs1[n0 + tid];
  }
  {  // xs: 512 float4, 2/thread
    int e = tid * 2;
    int c = e >> 3, off = (e & 7) * 4;
    *(float4*)&xs[c][off] = *(const float4*)&X[c * NPIX + n0 + off];
    int e1 = e + 1;
    int c1 = e1 >> 3, off1 = (e1 & 7) * 4;
    *(float4*)&xs[c1][off1] = *(const float4*)&X[c1 * NPIX + n0 + off1];
  }
  {  // wsh [k][m]
    int m = tid >> 2, kg = (tid & 3) * 16;
    const float4* wr = (const float4*)&W[(m0 + m) * 64 + kg];
    float4 w0 = wr[0], w1 = wr[1], w2 = wr[2], w3 = wr[3];
    float wv[16] = {w0.x, w0.y, w0.z, w0.w, w1.x, w1.y, w1.z, w1.w,
                    w2.x, w2.y, w2.z, w2.w, w3.x, w3.y, w3.z, w3.w};
#pragma unroll
    for (int j = 0; j < 16; j++) wsh[kg + j][m] = wv[j];
  }
  {  // h2s: 256 float4, 1/thread
    int k = tid >> 3, nf = (tid & 7) * 4;
    *(float4*)&h2s[k][nf] = *(const float4*)&h2[k * NPIX + n0 + nf];
  }
  {  // wgs/wbs [k][m]
    int m = tid >> 2, kg = (tid & 3) * 8;
    const float4* g0 = (const float4*)&gamW[m * 32 + kg];
    float4 a = g0[0], b4 = g0[1];
    float gv[8] = {a.x, a.y, a.z, a.w, b4.x, b4.y, b4.z, b4.w};
#pragma unroll
    for (int j = 0; j < 8; j++) wgs[kg + j][m] = gv[j];
    const float4* bb0 = (const float4*)&betW[m * 32 + kg];
    float4 c4 = bb0[0], d4 = bb0[1];
    float bv[8] = {c4.x, c4.y, c4.z, c4.w, d4.x, d4.y, d4.z, d4.w};
#pragma unroll
    for (int j = 0; j < 8; j++) wbs[kg + j][m] = bv[j];
  }
  __syncthreads();
  {  // LN apply in-place: thread = 1 ch x 8 px
    int c = tid >> 2, pg = (tid & 3) * 8;
    float wc = lnw[c], bc = lnb[c];
#pragma unroll
    for (int j = 0; j < 8; j++) {
      int p = pg + j;
      xs[c][p] = (xs[c][p] - mu[p]) * rs[p] * wc + bc;
    }
  }
  __syncthreads();
  int tx = tid & 15, ty = tid >> 4;  // tx: 2 px, ty: 4 ch
  float ga[4][2] = {}, ba[4][2] = {};
#pragma unroll 8
  for (int kk = 0; kk < 32; kk++) {
    float4 wg4 = *(const float4*)&wgs[kk][ty * 4];
    float4 wb4 = *(const float4*)&wbs[kk][ty * 4];
    float2 h22 = *(const float2*)&h2s[kk][tx * 2];
    float gv[4] = {wg4.x, wg4.y, wg4.z, wg4.w};
    float bv[4] = {wb4.x, wb4.y, wb4.z, wb4.w};
    float hv[2] = {h22.x, h22.y};
#pragma unroll
    for (int im = 0; im < 4; im++)
#pragma unroll
      for (int in = 0; in < 2; in++) {
        ga[im][in] = fmaf(gv[im], hv[in], ga[im][in]);
        ba[im][in] = fmaf(bv[im], hv[in], ba[im][in]);
      }
  }
#pragma unroll
  for (int im = 0; im < 4; im++) {
    int cc = ty * 4 + im;
    float gb = gamB[cc], bb2 = betB[cc];
#pragma unroll
    for (int in = 0; in < 2; in++) {
      ga[im][in] += gb;
      ba[im][in] += bb2;
    }
  }
  float acc[4][2] = {};
#pragma unroll 8
  for (int kk = 0; kk < 64; kk++) {
    float4 a = *(const float4*)&wsh[kk][ty * 4];
    float2 b2 = *(const float2*)&xs[kk][tx * 2];
    float av[4] = {a.x, a.y, a.z, a.w};
    float bv[2] = {b2.x, b2.y};
#pragma unroll
    for (int im = 0; im < 4; im++)
#pragma unroll
      for (int in = 0; in < 2; in++)
        acc[im][in] = fmaf(av[im], bv[in], acc[im][in]);
  }
  float val[4][2];
#pragma unroll
  for (int im = 0; im < 4; im++) {
    int cc = ty * 4 + im;
    float bv = bias[m0 + cc];
#pragma unroll
    for (int in = 0; in < 2; in++)
      val[im][in] = fmaf(ga[im][in], acc[im][in] + bv, ba[im][in]);
  }
  if (part == 0) {
    float msum = 0.f;
#pragma unroll
    for (int t = 0; t < 16; t++) msum += bsums[t];
    float mean = msum * (1.f / 4096.f);
    float a0 = alpha[0];
    const float2 pv = *(const float2*)&pooled[n0 + tx * 2];
    float iv[2] = {a0 * (pv.x - mean), a0 * (pv.y - mean)};
#pragma unroll
    for (int im = 0; im < 4; im++)
#pragma unroll
      for (int in = 0; in < 2; in++)
        val[im][in] = (val[im][in] + iv[in]) * QSCALE;
  }
  if (part < 2) {
    unsigned short* dst = (part == 0) ? qhl : khl;
    int h = ty >> 1, d0 = (ty & 1) * 4;
#pragma unroll
    for (int in = 0; in < 2; in++) {
      int n = n0 + tx * 2 + in;
      unsigned int pk[4];
#pragma unroll
      for (int im = 0; im < 4; im++) pk[im] = split_pack(val[im][in]);
      short4 hi, lo;
      hi.x = (short)(pk[0] & 0xffffu); hi.y = (short)(pk[1] & 0xffffu);
      hi.z = (short)(pk[2] & 0xffffu); hi.w = (short)(pk[3] & 0xffffu);
      lo.x = (short)(pk[0] >> 16); lo.y = (short)(pk[1] >> 16);
      lo.z = (short)(pk[2] >> 16); lo.w = (short)(pk[3] >> 16);
      unsigned short* base = dst + ((size_t)(h * NPIX + n) << 4) + d0;
      *(short4*)base = hi;
      *(short4*)(base + 8) = lo;
    }
  } else {
    int nq = n0 + tx * 2;
    int off0 = (nq >> 5) * 32 + ((nq >> 4) & 1) * 4 + ((nq >> 2) & 3) * 8 +
               (nq & 3);
#pragma unroll
    for (int im = 0; im < 4; im++) {
      int cc = ty * 4 + im;
      unsigned int pk0 = split_pack(val[im][0]);
      unsigned int pk1 = split_pack(val[im][1]);
      short2 hi, lo;
      hi.x = (short)(pk0 & 0xffffu);
      hi.y = (short)(pk1 & 0xffffu);
      lo.x = (short)(pk0 >> 16);
      lo.y = (short)(pk1 >> 16);
      *(short2*)(vthx + (size_t)cc * NPIX + off0) = hi;
      *(short2*)(vtlx + (size_t)cc * NPIX + off0) = lo;
    }
  }
}

// ---------------------------------------------------------------------------
// MFMA flash attention: 4 i-tiles per wave off one k/v stream (quarters the
// per-query k/v L2 traffic), JP=8 (512-j slices), zero LDS, no online max.
// grid (16 i-tiles of 256, 8 heads, 8 jp) = 1024 blocks (4/CU).
__global__ __launch_bounds__(256, 4) void attn_kernel(
    const unsigned short* __restrict__ qhl,
    const unsigned short* __restrict__ khl,
    const unsigned short* __restrict__ vthx,
    const unsigned short* __restrict__ vtlx,
    const unsigned short* __restrict__ cbuf, float* __restrict__ pacc,
    float* __restrict__ pl) {
  int tid = threadIdx.x;
  int wave = tid >> 6, lane = tid & 63;
  int g = lane >> 4, c = lane & 15;
  int h = blockIdx.y, jp = blockIdx.z;
  int i0 = blockIdx.x * 256 + wave * 64;
  int jbase = jp * 512;
  bf16x8 qB[4];
#pragma unroll
  for (int t = 0; t < 4; t++)
    qB[t] = *(const bf16x8*)(qhl + ((size_t)(h * NPIX + i0 + t * 16 + c) << 4) +
                             ((g & 1) << 3));
  const unsigned short* kp =
      khl + ((size_t)(h * NPIX + jbase + c) << 4) + ((g >> 1) << 3);
  const unsigned short* vhp;
  const unsigned short* vlp;
  int vstep;
  if (c < 8) {
    vhp = vthx + (size_t)(h * 8 + c) * NPIX + jbase + (g << 3);
    vlp = vtlx + (size_t)(h * 8 + c) * NPIX + jbase + (g << 3);
    vstep = 32;
  } else {
    vhp = (c == 8) ? cbuf : (cbuf + 8);  // ones row / zero rows
    vlp = cbuf + 8;
    vstep = 0;
  }
  floatx4 zero4 = {0.f, 0.f, 0.f, 0.f};
  floatx4 aH[4], aM[4];
#pragma unroll
  for (int t = 0; t < 4; t++) {
    aH[t] = zero4;
    aM[t] = zero4;
  }
#pragma unroll 2
  for (int jt = 0; jt < 16; ++jt) {
    bf16x8 ka0 = *(const bf16x8*)kp;
    bf16x8 ka1 = *(const bf16x8*)(kp + 256);
    bf16x8 avh = *(const bf16x8*)vhp;
    bf16x8 avl = *(const bf16x8*)vlp;
    kp += 512;
    vhp += vstep;
    vlp += vstep;
#pragma unroll
    for (int t = 0; t < 4; t++) {
      floatx4 s0 =
          __builtin_amdgcn_mfma_f32_16x16x32_bf16(ka0, qB[t], zero4, 0, 0, 0);
      floatx4 s1 =
          __builtin_amdgcn_mfma_f32_16x16x32_bf16(ka1, qB[t], zero4, 0, 0, 0);
      float p0 = __builtin_amdgcn_exp2f(fminf(s0[0], 80.f));
      float p1 = __builtin_amdgcn_exp2f(fminf(s0[1], 80.f));
      float p2 = __builtin_amdgcn_exp2f(fminf(s0[2], 80.f));
      float p3 = __builtin_amdgcn_exp2f(fminf(s0[3], 80.f));
      float p4 = __builtin_amdgcn_exp2f(fminf(s1[0], 80.f));
      float p5 = __builtin_amdgcn_exp2f(fminf(s1[1], 80.f));
      float p6 = __builtin_amdgcn_exp2f(fminf(s1[2], 80.f));
      float p7 = __builtin_amdgcn_exp2f(fminf(s1[3], 80.f));
      uintx4 bh;
      bh.x = hi_pair(p0, p1);
      bh.y = hi_pair(p2, p3);
      bh.z = hi_pair(p4, p5);
      bh.w = hi_pair(p6, p7);
      bf16x8 pbh = __builtin_bit_cast(bf16x8, bh);
      aH[t] = __builtin_amdgcn_mfma_f32_16x16x32_bf16(avh, pbh, aH[t], 0, 0, 0);
      aM[t] = __builtin_amdgcn_mfma_f32_16x16x32_bf16(avl, pbh, aM[t], 0, 0, 0);
    }
  }
#pragma unroll
  for (int t = 0; t < 4; t++) {
    floatx4 o = aH[t] + aM[t];
    if (g < 2) {
      size_t b0 = (size_t)((jp * 8 + h) * NPIX + i0 + t * 16 + c);
      *(float4*)&pacc[b0 * 8 + g * 4] = make_float4(o[0], o[1], o[2], o[3]);
    } else if (g == 2) {
      pl[(size_t)((jp * 8 + h) * NPIX + i0 + t * 16 + c)] = o[0];
    }
  }
}

// ---------------------------------------------------------------------------
// Fused: combine 8 j-partitions -> proj GEMM + residual -> x1 (ch==0) + LN2
// stats -> LN -> one 64-ch slice of ffn1 -> f1. grid (128, 4).
__global__ __launch_bounds__(256) void proj_ffn1_kernel(
    const float* __restrict__ pacc, const float* __restrict__ pl,
    const float* __restrict__ Wp, const float* __restrict__ bp,
    const float* __restrict__ x, const float* __restrict__ ln2w,
    const float* __restrict__ ln2b, const float* __restrict__ W1,
    const float* __restrict__ b1f, float* __restrict__ x1,
    float* __restrict__ f1) {
  __shared__ float at[64][33];
  __shared__ float wsh[64][64];
  __shared__ float xsl[64][33];
  __shared__ float ps[8][33];
  __shared__ float pq[8][33];
  __shared__ float mus[32];
  __shared__ float rss[32];
  int n0 = blockIdx.x * 32;
  int ch = blockIdx.y;
  int tid = threadIdx.x;
  {
    int mm = tid >> 2, kg = (tid & 3) * 16;
    const float4* wr = (const float4*)&Wp[mm * 64 + kg];
    float4 w0 = wr[0], w1 = wr[1], w2 = wr[2], w3 = wr[3];
    float wv[16] = {w0.x, w0.y, w0.z, w0.w, w1.x, w1.y, w1.z, w1.w,
                    w2.x, w2.y, w2.z, w2.w, w3.x, w3.y, w3.z, w3.w};
#pragma unroll
    for (int j = 0; j < 16; j++) wsh[kg + j][mm] = wv[j];
  }
  {
    int hh = tid >> 5, nn = tid & 31;
    int i = n0 + nn;
    float L = 0.f, o[8] = {};
#pragma unroll
    for (int p = 0; p < 8; p++) {
      size_t base = (size_t)((p * 8 + hh) * NPIX + i);
      L += pl[base];
      const float4 a0 = *(const float4*)&pacc[base * 8];
      const float4 a1 = *(const float4*)&pacc[base * 8 + 4];
      o[0] += a0.x; o[1] += a0.y; o[2] += a0.z; o[3] += a0.w;
      o[4] += a1.x; o[5] += a1.y; o[6] += a1.z; o[7] += a1.w;
    }
    float inv = 1.f / L;
#pragma unroll
    for (int d = 0; d < 8; d++) at[hh * 8 + d][nn] = o[d] * inv;
  }
  __syncthreads();
  int ty = tid >> 5, tx = tid & 31;
  float acc[8] = {};
#pragma unroll 8
  for (int k = 0; k < 64; k++) {
    float b = at[k][tx];
    float4 a0 = *(const float4*)&wsh[k][ty * 8];
    float4 a1 = *(const float4*)&wsh[k][ty * 8 + 4];
    acc[0] = fmaf(a0.x, b, acc[0]);
    acc[1] = fmaf(a0.y, b, acc[1]);
    acc[2] = fmaf(a0.z, b, acc[2]);
    acc[3] = fmaf(a0.w, b, acc[3]);
    acc[4] = fmaf(a1.x, b, acc[4]);
    acc[5] = fmaf(a1.y, b, acc[5]);
    acc[6] = fmaf(a1.z, b, acc[6]);
    acc[7] = fmaf(a1.w, b, acc[7]);
  }
  float v[8], sn = 0.f, qn = 0.f;
#pragma unroll
  for (int im = 0; im < 8; im++) {
    int row = ty * 8 + im;
    float vv = acc[im] + bp[row] + x[row * NPIX + n0 + tx];
    v[im] = vv;
    sn += vv;
    qn = fmaf(vv, vv, qn);
  }
  if (ch == 0) {
#pragma unroll
    for (int im = 0; im < 8; im++)
      x1[(ty * 8 + im) * NPIX + n0 + tx] = v[im];
  }
  ps[ty][tx] = sn;
  pq[ty][tx] = qn;
  __syncthreads();
  if (tid < 32) {
    float s = 0.f, q = 0.f;
#pragma unroll
    for (int t = 0; t < 8; t++) {
      s += ps[t][tid];
      q += pq[t][tid];
    }
    float mu = s * (1.f / 64.f);
    mus[tid] = mu;
    rss[tid] = rsqrtf(q * (1.f / 64.f) - mu * mu + 1e-5f);
  }
  __syncthreads();
  {
    float muv = mus[tx], rsv = rss[tx];
#pragma unroll
    for (int im = 0; im < 8; im++) {
      int row = ty * 8 + im;
      xsl[row][tx] = (v[im] - muv) * rsv * ln2w[row] + ln2b[row];
    }
  }
  {
    int mm = tid >> 2, kg = (tid & 3) * 16;
    const float4* wr = (const float4*)&W1[(ch * 64 + mm) * 64 + kg];
    float4 w0 = wr[0], w1 = wr[1], w2 = wr[2], w3 = wr[3];
    float wv[16] = {w0.x, w0.y, w0.z, w0.w, w1.x, w1.y, w1.z, w1.w,
                    w2.x, w2.y, w2.z, w2.w, w3.x, w3.y, w3.z, w3.w};
#pragma unroll
    for (int j = 0; j < 16; j++) wsh[kg + j][mm] = wv[j];
  }
  __syncthreads();
  float a2[8] = {};
#pragma unroll 8
  for (int k = 0; k < 64; k++) {
    float b = xsl[k][tx];
    float4 a0 = *(const float4*)&wsh[k][ty * 8];
    float4 a1 = *(const float4*)&wsh[k][ty * 8 + 4];
    a2[0] = fmaf(a0.x, b, a2[0]);
    a2[1] = fmaf(a0.y, b, a2[1]);
    a2[2] = fmaf(a0.z, b, a2[2]);
    a2[3] = fmaf(a0.w, b, a2[3]);
    a2[4] = fmaf(a1.x, b, a2[4]);
    a2[5] = fmaf(a1.y, b, a2[5]);
    a2[6] = fmaf(a1.z, b, a2[6]);
    a2[7] = fmaf(a1.w, b, a2[7]);
  }
#pragma unroll
  for (int im = 0; im < 8; im++) {
    int row = ch * 64 + ty * 8 + im;
    f1[row * NPIX + n0 + tx] = a2[im] + b1f[row];
  }
}

// ---------------------------------------------------------------------------
// Depthwise 3x3 + exact GELU; 4 horizontal px/thread (unchanged).
__global__ __launch_bounds__(256) void dw_gelu_kernel(
    const float* __restrict__ f1, const float* __restrict__ w,
    const float* __restrict__ b, float* __restrict__ f2) {
  int t = blockIdx.x * 256 + threadIdx.x;
  int c = t >> 10, pq = t & 1023;
  int py = pq >> 4, px0 = (pq & 15) << 2;
  const float* base = f1 + c * NPIX;
  float wv[9];
#pragma unroll
  for (int i = 0; i < 9; i++) wv[i] = w[c * 9 + i];
  float bc = b[c];
  float a[4] = {bc, bc, bc, bc};
#pragma unroll
  for (int dy = 0; dy < 3; dy++) {
    int y = py + dy - 1;
    if (y < 0 || y > 63) continue;
    const float* row = base + y * IMG + px0;
    float4 mid = *(const float4*)row;
    float left = (px0 > 0) ? row[-1] : 0.f;
    float right = (px0 < 60) ? row[4] : 0.f;
    float win[6] = {left, mid.x, mid.y, mid.z, mid.w, right};
#pragma unroll
    for (int o = 0; o < 4; o++)
#pragma unroll
      for (int dx = 0; dx < 3; dx++)
        a[o] = fmaf(wv[dy * 3 + dx], win[o + dx], a[o]);
  }
  float4 o4;
  float* op = &o4.x;
#pragma unroll
  for (int o = 0; o < 4; o++)
    op[o] = 0.5f * a[o] * (1.f + erff(a[o] * 0.70710678118654752f));
  *(float4*)&f2[c * NPIX + py * IMG + px0] = o4;
}

// ---------------------------------------------------------------------------
// ffn2 GEMM, single-barrier full-K staging: out = W[64][256]*f2 + bias + x1.
__global__ __launch_bounds__(256) void ffn2_kernel(
    const float* __restrict__ W, const float* __restrict__ X,
    const float* __restrict__ bias, const float* __restrict__ resid,
    float* __restrict__ C) {
  __shared__ float xs[256][32];
  __shared__ float wsh[256][16];
  int n0 = blockIdx.x * 32, m0 = blockIdx.y * 16;
  int tid = threadIdx.x;
#pragma unroll
  for (int e = tid; e < 2048; e += 256) {
    int k = e >> 3, nf = (e & 7) * 4;
    *(float4*)&xs[k][nf] = *(const float4*)&X[k * NPIX + n0 + nf];
  }
#pragma unroll
  for (int e = tid; e < 4096; e += 256) {
    int mm = e >> 8, kk = e & 255;
    wsh[kk][mm] = W[(m0 + mm) * 256 + kk];
  }
  __syncthreads();
  int m = tid >> 4, np = (tid & 15) * 2;
  float acc0 = 0.f, acc1 = 0.f;
#pragma unroll 8
  for (int kk = 0; kk < 256; kk++) {
    float a = wsh[kk][m];
    float2 b2 = *(const float2*)&xs[kk][np];
    acc0 = fmaf(a, b2.x, acc0);
    acc1 = fmaf(a, b2.y, acc1);
  }
  int row = m0 + m;
  float bv = bias[row];
  const float2 r2 = *(const float2*)&resid[row * NPIX + n0 + np];
  float2 o = make_float2(acc0 + bv + r2.x, acc1 + bv + r2.y);
  *(float2*)&C[row * NPIX + n0 + np] = o;
}

// ---------------------------------------------------------------------------
extern "C" void kernel_launch(void* const* d_in, const int* in_sizes, int n_in,
                              void* d_out, int out_size, void* d_ws,
                              size_t ws_size, hipStream_t stream) {
  const float* x      = (const float*)d_in[0];
  const float* luma   = (const float*)d_in[1];
  const float* ln1_w  = (const float*)d_in[2];
  const float* ln1_b  = (const float*)d_in[3];
  const float* qkv_w  = (const float*)d_in[4];
  const float* qkv_b  = (const float*)d_in[5];
  const float* proj_w = (const float*)d_in[6];
  const float* proj_b = (const float*)d_in[7];
  const float* lc1_w  = (const float*)d_in[8];
  const float* lc1_b  = (const float*)d_in[9];
  const float* lc2_w  = (const float*)d_in[10];
  const float* lc2_b  = (const float*)d_in[11];
  const float* gam_w  = (const float*)d_in[12];
  const float* gam_b  = (const float*)d_in[13];
  const float* bet_w  = (const float*)d_in[14];
  const float* bet_b  = (const float*)d_in[15];
  const float* alpha  = (const float*)d_in[16];
  const float* ln2_w  = (const float*)d_in[17];
  const float* ln2_b  = (const float*)d_in[18];
  const float* ffn1_w = (const float*)d_in[19];
  const float* ffn1_b = (const float*)d_in[20];
  const float* dw_w   = (const float*)d_in[21];
  const float* dw_b   = (const float*)d_in[22];
  const float* ffn2_w = (const float*)d_in[23];
  const float* ffn2_b = (const float*)d_in[24];
  float* out = (float*)d_out;

  float* w = (float*)d_ws;
  float* pooled = w + 0;        // 4096
  float* bsums  = w + 4096;     // 64 (16 used)
  unsigned short* cbuf = (unsigned short*)(w + 4160);     // 64 f (16 us used)
  float* mu1 = w + 4224;        // 4096
  float* rs1 = w + 8320;        // 4096
  unsigned short* qhl  = (unsigned short*)(w + 12416);    // 262144 f
  unsigned short* khl  = (unsigned short*)(w + 274560);   // 262144 f
  unsigned short* vthx = (unsigned short*)(w + 536704);   // 131072 f
  unsigned short* vtlx = (unsigned short*)(w + 667776);   // 131072 f
  float* pacc = w + 798848;    // 2097152 (JP=8)
  float* pl   = w + 2896000;   // 262144
  float* x1   = w + 3158144;   // 262144
  float* f1   = w + 3420288;   // 1048576
  float* f2   = w + 4468864;   // 1048576
  float* h2   = w + 5517440;   // 131072
  float* h1   = w + 5648512;   // 131072

  lc1_kernel<<<dim3(16, 8), 256, 0, stream>>>(luma, lc1_w, lc1_b, h1, pooled,
                                              bsums, cbuf);
  lc2_kernel<<<dim3(16, 8), 256, 0, stream>>>(h1, lc2_w, lc2_b, x, h2, mu1,
                                              rs1);
  ln_qkv_kernel<<<dim3(128, 3), 256, 0, stream>>>(
      x, mu1, rs1, ln1_w, ln1_b, qkv_w, qkv_b, gam_w, gam_b, bet_w, bet_b, h2,
      pooled, bsums, alpha, qhl, khl, vthx, vtlx);
  attn_kernel<<<dim3(16, 8, 8), 256, 0, stream>>>(qhl, khl, vthx, vtlx, cbuf,
                                                  pacc, pl);
  proj_ffn1_kernel<<<dim3(128, 4), 256, 0, stream>>>(
      pacc, pl, proj_w, proj_b, x, ln2_w, ln2_b, ffn1_w, ffn1_b, x1, f1);
  dw_gelu_kernel<<<1024, 256, 0, stream>>>(f1, dw_w, dw_b, f2);
  ffn2_kernel<<<dim3(128, 4), 256, 0, stream>>>(ffn2_w, f2, ffn2_b, x1, out);
}

// Round 12
// 195.870 us; speedup vs baseline: 1.0511x; 1.0337x over previous
//
#include <hip/hip_runtime.h>
#include <math.h>

// B=1, C=64, H=W=64, N=4096, heads=8, dh=8, inner=64, hid_lc=32, hid_f=256.
#define NPIX 4096
#define IMG 64

typedef __attribute__((ext_vector_type(8))) short bf16x8;
typedef __attribute__((ext_vector_type(4))) float floatx4;
typedef __attribute__((ext_vector_type(4))) unsigned int uintx4;

// fp32 -> (hi bf16 in low16) | (lo bf16 in high16), lo = x - f32(hi)
__device__ __forceinline__ unsigned int split_pack(float x) {
  unsigned int u = __float_as_uint(x);
  unsigned int hif = u & 0xffff0000u;
  float lof = x - __uint_as_float(hif);
  return (u >> 16) | (__float_as_uint(lof) & 0xffff0000u);
}

// pack hi16 of two floats: low16 = hi16(a), high16 = hi16(b)
__device__ __forceinline__ unsigned int hi_pair(float a, float b) {
  return (__float_as_uint(a) >> 16) | (__float_as_uint(b) & 0xffff0000u);
}

// ---------------------------------------------------------------------------
// Merged lc1+lc2: stage 20x20 luma halo (1 load/pos), compute h1 18x18x32
// halo in LDS, then lc2 conv -> h2. ocg==0 blocks also emit pooled + tile
// sums + LN1 stats; block (0,0) inits the attn constant buffer.
// grid (16 px-tiles of 16x16, 8 ocg of 4).
__global__ __launch_bounds__(256) void lc12_kernel(
    const float* __restrict__ luma, const float* __restrict__ w1,
    const float* __restrict__ b1, const float* __restrict__ w2,
    const float* __restrict__ b2, const float* __restrict__ x,
    float* __restrict__ h2, float* __restrict__ pooled,
    float* __restrict__ bsums, float* __restrict__ mu1,
    float* __restrict__ rs1, unsigned short* __restrict__ cbuf) {
  __shared__ float lum[400];      // 20x20: (ty0-2..+17, tx0-2..+17)
  __shared__ float sw1[288];      // lc1 weights 32x9
  __shared__ float tin[32][324];  // h1 on 18x18 halo per ic
  __shared__ float swt[4][32][9];
  __shared__ float red[256];
  int tile = blockIdx.x, ocg = blockIdx.y;
  int ty0 = (tile >> 2) * 16, tx0 = (tile & 3) * 16;
  int tid = threadIdx.x;
  if (tile == 0 && ocg == 0 && tid < 16) cbuf[tid] = (tid < 8) ? 0x3F80 : 0;
  for (int idx = tid; idx < 400; idx += 256) {
    int py = idx / 20, px = idx - py * 20;
    int gy = ty0 + py - 2, gx = tx0 + px - 2;
    lum[idx] = (gy >= 0 && gy < IMG && gx >= 0 && gx < IMG)
                   ? luma[gy * IMG + gx]
                   : 0.f;
  }
  for (int idx = tid; idx < 288; idx += 256) sw1[idx] = w1[idx];
  for (int idx = tid; idx < 1152; idx += 256) {
    int o = idx / 288, r = idx - o * 288;
    swt[o][r / 9][r % 9] = w2[(ocg * 4 + o) * 288 + r];
  }
  __syncthreads();
  // h1 halo: h1(gy,gx) = relu(b1 + conv3x3(luma)); zero outside image.
  for (int idx = tid; idx < 32 * 324; idx += 256) {
    int ic = idx / 324, pos = idx - ic * 324;
    int py = pos / 18, px = pos - py * 18;
    int gy = ty0 + py - 1, gx = tx0 + px - 1;
    float v = 0.f;
    if (gy >= 0 && gy < IMG && gx >= 0 && gx < IMG) {
      float s = b1[ic];
      const float* wp = &sw1[ic * 9];
#pragma unroll
      for (int dy = 0; dy < 3; dy++)
#pragma unroll
        for (int dx = 0; dx < 3; dx++)
          s = fmaf(wp[dy * 3 + dx], lum[(py + dy) * 20 + px + dx], s);
      v = fmaxf(s, 0.f);
    }
    tin[ic][pos] = v;
  }
  __syncthreads();
  int ly = tid >> 4, lx = tid & 15;
  int p = (ty0 + ly) * IMG + tx0 + lx;
  float acc[4];
#pragma unroll
  for (int o = 0; o < 4; o++) acc[o] = b2[ocg * 4 + o];
  for (int ic = 0; ic < 32; ic++) {
    float v[9];
#pragma unroll
    for (int dy = 0; dy < 3; dy++)
#pragma unroll
      for (int dx = 0; dx < 3; dx++)
        v[dy * 3 + dx] = tin[ic][(ly + dy) * 18 + lx + dx];
#pragma unroll
    for (int o = 0; o < 4; o++)
#pragma unroll
      for (int t = 0; t < 9; t++) acc[o] = fmaf(swt[o][ic][t], v[t], acc[o]);
  }
#pragma unroll
  for (int o = 0; o < 4; o++)
    h2[(ocg * 4 + o) * NPIX + p] = fmaxf(acc[o], 0.f);
  if (ocg == 0) {
    int gy = ty0 + ly, gx = tx0 + lx;
    float sv = 0.f;
#pragma unroll
    for (int dy = 0; dy < 3; dy++)
#pragma unroll
      for (int dx = 0; dx < 3; dx++)
        sv += lum[(ly + dy + 1) * 20 + lx + dx + 1];
    float cy = 3.f - (gy == 0 ? 1.f : 0.f) - (gy == 63 ? 1.f : 0.f);
    float cx = 3.f - (gx == 0 ? 1.f : 0.f) - (gx == 63 ? 1.f : 0.f);
    float pv = (cy * cx - sv) * (1.f / 9.f);
    pooled[p] = pv;
    red[tid] = pv;
    __syncthreads();
    for (int st = 128; st > 0; st >>= 1) {
      if (tid < st) red[tid] += red[tid + st];
      __syncthreads();
    }
    if (tid == 0) bsums[tile] = red[0];
    float s = 0.f, q = 0.f;
#pragma unroll 8
    for (int cc = 0; cc < 64; cc++) {
      float xv = x[cc * NPIX + p];
      s += xv;
      q = fmaf(xv, xv, q);
    }
    float mu = s * (1.f / 64.f);
    mu1[p] = mu;
    rs1[p] = rsqrtf(q * (1.f / 64.f) - mu * mu + 1e-5f);
  }
}

// ---------------------------------------------------------------------------
// Fused per-pixel LayerNorm (precomputed stats) + qkv 1x1 GEMM + (gam/bet
// GEMMs in-register) + modulation + hi/lo split store.
// 32-px n-tiles: grid (128, 3). Thread = 4 ch x 2 px. (unchanged from r11)
__global__ __launch_bounds__(256) void ln_qkv_kernel(
    const float* __restrict__ X, const float* __restrict__ mu1,
    const float* __restrict__ rs1, const float* __restrict__ lnw,
    const float* __restrict__ lnb, const float* __restrict__ W,
    const float* __restrict__ bias, const float* __restrict__ gamW,
    const float* __restrict__ gamB, const float* __restrict__ betW,
    const float* __restrict__ betB, const float* __restrict__ h2,
    const float* __restrict__ pooled, const float* __restrict__ bsums,
    const float* __restrict__ alpha, unsigned short* __restrict__ qhl,
    unsigned short* __restrict__ khl, unsigned short* __restrict__ vthx,
    unsigned short* __restrict__ vtlx) {
  const float QSCALE = 0.35355339059327376f * 1.4426950408889634f;
  __shared__ float xs[64][32];
  __shared__ float wsh[64][64];
  __shared__ float h2s[32][32];
  __shared__ float wgs[32][64];
  __shared__ float wbs[32][64];
  __shared__ float mu[32];
  __shared__ float rs[32];
  int n0 = blockIdx.x * 32, part = blockIdx.y, m0 = part * 64;
  int tid = threadIdx.x;
  if (tid < 32) {
    mu[tid] = mu1[n0 + tid];
    rs[tid] = rs1[n0 + tid];
  }
  {
    int e = tid * 2;
    int c = e >> 3, off = (e & 7) * 4;
    *(float4*)&xs[c][off] = *(const float4*)&X[c * NPIX + n0 + off];
    int e1 = e + 1;
    int c1 = e1 >> 3, off1 = (e1 & 7) * 4;
    *(float4*)&xs[c1][off1] = *(const float4*)&X[c1 * NPIX + n0 + off1];
  }
  {
    int m = tid >> 2, kg = (tid & 3) * 16;
    const float4* wr = (const float4*)&W[(m0 + m) * 64 + kg];
    float4 w0 = wr[0], w1 = wr[1], w2 = wr[2], w3 = wr[3];
    float wv[16] = {w0.x, w0.y, w0.z, w0.w, w1.x, w1.y, w1.z, w1.w,
                    w2.x, w2.y, w2.z, w2.w, w3.x, w3.y, w3.z, w3.w};
#pragma unroll
    for (int j = 0; j < 16; j++) wsh[kg + j][m] = wv[j];
  }
  {
    int k = tid >> 3, nf = (tid & 7) * 4;
    *(float4*)&h2s[k][nf] = *(const float4*)&h2[k * NPIX + n0 + nf];
  }
  {
    int m = tid >> 2, kg = (tid & 3) * 8;
    const float4* g0 = (const float4*)&gamW[m * 32 + kg];
    float4 a = g0[0], b4 = g0[1];
    float gv[8] = {a.x, a.y, a.z, a.w, b4.x, b4.y, b4.z, b4.w};
#pragma unroll
    for (int j = 0; j < 8; j++) wgs[kg + j][m] = gv[j];
    const float4* bb0 = (const float4*)&betW[m * 32 + kg];
    float4 c4 = bb0[0], d4 = bb0[1];
    float bv[8] = {c4.x, c4.y, c4.z, c4.w, d4.x, d4.y, d4.z, d4.w};
#pragma unroll
    for (int j = 0; j < 8; j++) wbs[kg + j][m] = bv[j];
  }
  __syncthreads();
  {
    int c = tid >> 2, pg = (tid & 3) * 8;
    float wc = lnw[c], bc = lnb[c];
#pragma unroll
    for (int j = 0; j < 8; j++) {
      int p = pg + j;
      xs[c][p] = (xs[c][p] - mu[p]) * rs[p] * wc + bc;
    }
  }
  __syncthreads();
  int tx = tid & 15, ty = tid >> 4;
  float ga[4][2] = {}, ba[4][2] = {};
#pragma unroll 8
  for (int kk = 0; kk < 32; kk++) {
    float4 wg4 = *(const float4*)&wgs[kk][ty * 4];
    float4 wb4 = *(const float4*)&wbs[kk][ty * 4];
    float2 h22 = *(const float2*)&h2s[kk][tx * 2];
    float gv[4] = {wg4.x, wg4.y, wg4.z, wg4.w};
    float bv[4] = {wb4.x, wb4.y, wb4.z, wb4.w};
    float hv[2] = {h22.x, h22.y};
#pragma unroll
    for (int im = 0; im < 4; im++)
#pragma unroll
      for (int in = 0; in < 2; in++) {
        ga[im][in] = fmaf(gv[im], hv[in], ga[im][in]);
        ba[im][in] = fmaf(bv[im], hv[in], ba[im][in]);
      }
  }
#pragma unroll
  for (int im = 0; im < 4; im++) {
    int cc = ty * 4 + im;
    float gb = gamB[cc], bb2 = betB[cc];
#pragma unroll
    for (int in = 0; in < 2; in++) {
      ga[im][in] += gb;
      ba[im][in] += bb2;
    }
  }
  float acc[4][2] = {};
#pragma unroll 8
  for (int kk = 0; kk < 64; kk++) {
    float4 a = *(const float4*)&wsh[kk][ty * 4];
    float2 b2 = *(const float2*)&xs[kk][tx * 2];
    float av[4] = {a.x, a.y, a.z, a.w};
    float bv[2] = {b2.x, b2.y};
#pragma unroll
    for (int im = 0; im < 4; im++)
#pragma unroll
      for (int in = 0; in < 2; in++)
        acc[im][in] = fmaf(av[im], bv[in], acc[im][in]);
  }
  float val[4][2];
#pragma unroll
  for (int im = 0; im < 4; im++) {
    int cc = ty * 4 + im;
    float bv = bias[m0 + cc];
#pragma unroll
    for (int in = 0; in < 2; in++)
      val[im][in] = fmaf(ga[im][in], acc[im][in] + bv, ba[im][in]);
  }
  if (part == 0) {
    float msum = 0.f;
#pragma unroll
    for (int t = 0; t < 16; t++) msum += bsums[t];
    float mean = msum * (1.f / 4096.f);
    float a0 = alpha[0];
    const float2 pv = *(const float2*)&pooled[n0 + tx * 2];
    float iv[2] = {a0 * (pv.x - mean), a0 * (pv.y - mean)};
#pragma unroll
    for (int im = 0; im < 4; im++)
#pragma unroll
      for (int in = 0; in < 2; in++)
        val[im][in] = (val[im][in] + iv[in]) * QSCALE;
  }
  if (part < 2) {
    unsigned short* dst = (part == 0) ? qhl : khl;
    int h = ty >> 1, d0 = (ty & 1) * 4;
#pragma unroll
    for (int in = 0; in < 2; in++) {
      int n = n0 + tx * 2 + in;
      unsigned int pk[4];
#pragma unroll
      for (int im = 0; im < 4; im++) pk[im] = split_pack(val[im][in]);
      short4 hi, lo;
      hi.x = (short)(pk[0] & 0xffffu); hi.y = (short)(pk[1] & 0xffffu);
      hi.z = (short)(pk[2] & 0xffffu); hi.w = (short)(pk[3] & 0xffffu);
      lo.x = (short)(pk[0] >> 16); lo.y = (short)(pk[1] >> 16);
      lo.z = (short)(pk[2] >> 16); lo.w = (short)(pk[3] >> 16);
      unsigned short* base = dst + ((size_t)(h * NPIX + n) << 4) + d0;
      *(short4*)base = hi;
      *(short4*)(base + 8) = lo;
    }
  } else {
    int nq = n0 + tx * 2;
    int off0 = (nq >> 5) * 32 + ((nq >> 4) & 1) * 4 + ((nq >> 2) & 3) * 8 +
               (nq & 3);
#pragma unroll
    for (int im = 0; im < 4; im++) {
      int cc = ty * 4 + im;
      unsigned int pk0 = split_pack(val[im][0]);
      unsigned int pk1 = split_pack(val[im][1]);
      short2 hi, lo;
      hi.x = (short)(pk0 & 0xffffu);
      hi.y = (short)(pk1 & 0xffffu);
      lo.x = (short)(pk0 >> 16);
      lo.y = (short)(pk1 >> 16);
      *(short2*)(vthx + (size_t)cc * NPIX + off0) = hi;
      *(short2*)(vtlx + (size_t)cc * NPIX + off0) = lo;
    }
  }
}

// ---------------------------------------------------------------------------
// MFMA flash attention (unchanged from r11): 4 i-tiles/wave, JP=8, zero LDS.
// grid (16 i-tiles of 256, 8 heads, 8 jp).
__global__ __launch_bounds__(256, 4) void attn_kernel(
    const unsigned short* __restrict__ qhl,
    const unsigned short* __restrict__ khl,
    const unsigned short* __restrict__ vthx,
    const unsigned short* __restrict__ vtlx,
    const unsigned short* __restrict__ cbuf, float* __restrict__ pacc,
    float* __restrict__ pl) {
  int tid = threadIdx.x;
  int wave = tid >> 6, lane = tid & 63;
  int g = lane >> 4, c = lane & 15;
  int h = blockIdx.y, jp = blockIdx.z;
  int i0 = blockIdx.x * 256 + wave * 64;
  int jbase = jp * 512;
  bf16x8 qB[4];
#pragma unroll
  for (int t = 0; t < 4; t++)
    qB[t] = *(const bf16x8*)(qhl + ((size_t)(h * NPIX + i0 + t * 16 + c) << 4) +
                             ((g & 1) << 3));
  const unsigned short* kp =
      khl + ((size_t)(h * NPIX + jbase + c) << 4) + ((g >> 1) << 3);
  const unsigned short* vhp;
  const unsigned short* vlp;
  int vstep;
  if (c < 8) {
    vhp = vthx + (size_t)(h * 8 + c) * NPIX + jbase + (g << 3);
    vlp = vtlx + (size_t)(h * 8 + c) * NPIX + jbase + (g << 3);
    vstep = 32;
  } else {
    vhp = (c == 8) ? cbuf : (cbuf + 8);  // ones row / zero rows
    vlp = cbuf + 8;
    vstep = 0;
  }
  floatx4 zero4 = {0.f, 0.f, 0.f, 0.f};
  floatx4 aH[4], aM[4];
#pragma unroll
  for (int t = 0; t < 4; t++) {
    aH[t] = zero4;
    aM[t] = zero4;
  }
#pragma unroll 2
  for (int jt = 0; jt < 16; ++jt) {
    bf16x8 ka0 = *(const bf16x8*)kp;
    bf16x8 ka1 = *(const bf16x8*)(kp + 256);
    bf16x8 avh = *(const bf16x8*)vhp;
    bf16x8 avl = *(const bf16x8*)vlp;
    kp += 512;
    vhp += vstep;
    vlp += vstep;
#pragma unroll
    for (int t = 0; t < 4; t++) {
      floatx4 s0 =
          __builtin_amdgcn_mfma_f32_16x16x32_bf16(ka0, qB[t], zero4, 0, 0, 0);
      floatx4 s1 =
          __builtin_amdgcn_mfma_f32_16x16x32_bf16(ka1, qB[t], zero4, 0, 0, 0);
      float p0 = __builtin_amdgcn_exp2f(fminf(s0[0], 80.f));
      float p1 = __builtin_amdgcn_exp2f(fminf(s0[1], 80.f));
      float p2 = __builtin_amdgcn_exp2f(fminf(s0[2], 80.f));
      float p3 = __builtin_amdgcn_exp2f(fminf(s0[3], 80.f));
      float p4 = __builtin_amdgcn_exp2f(fminf(s1[0], 80.f));
      float p5 = __builtin_amdgcn_exp2f(fminf(s1[1], 80.f));
      float p6 = __builtin_amdgcn_exp2f(fminf(s1[2], 80.f));
      float p7 = __builtin_amdgcn_exp2f(fminf(s1[3], 80.f));
      uintx4 bh;
      bh.x = hi_pair(p0, p1);
      bh.y = hi_pair(p2, p3);
      bh.z = hi_pair(p4, p5);
      bh.w = hi_pair(p6, p7);
      bf16x8 pbh = __builtin_bit_cast(bf16x8, bh);
      aH[t] = __builtin_amdgcn_mfma_f32_16x16x32_bf16(avh, pbh, aH[t], 0, 0, 0);
      aM[t] = __builtin_amdgcn_mfma_f32_16x16x32_bf16(avl, pbh, aM[t], 0, 0, 0);
    }
  }
#pragma unroll
  for (int t = 0; t < 4; t++) {
    floatx4 o = aH[t] + aM[t];
    if (g < 2) {
      size_t b0 = (size_t)((jp * 8 + h) * NPIX + i0 + t * 16 + c);
      *(float4*)&pacc[b0 * 8 + g * 4] = make_float4(o[0], o[1], o[2], o[3]);
    } else if (g == 2) {
      pl[(size_t)((jp * 8 + h) * NPIX + i0 + t * 16 + c)] = o[0];
    }
  }
}

// ---------------------------------------------------------------------------
// Fused: combine 8 j-partitions -> proj GEMM + residual -> x1 (ch==0) + LN2
// stats -> LN -> one 64-ch slice of ffn1 -> f1. grid (128, 4). (unchanged)
__global__ __launch_bounds__(256) void proj_ffn1_kernel(
    const float* __restrict__ pacc, const float* __restrict__ pl,
    const float* __restrict__ Wp, const float* __restrict__ bp,
    const float* __restrict__ x, const float* __restrict__ ln2w,
    const float* __restrict__ ln2b, const float* __restrict__ W1,
    const float* __restrict__ b1f, float* __restrict__ x1,
    float* __restrict__ f1) {
  __shared__ float at[64][33];
  __shared__ float wsh[64][64];
  __shared__ float xsl[64][33];
  __shared__ float ps[8][33];
  __shared__ float pq[8][33];
  __shared__ float mus[32];
  __shared__ float rss[32];
  int n0 = blockIdx.x * 32;
  int ch = blockIdx.y;
  int tid = threadIdx.x;
  {
    int mm = tid >> 2, kg = (tid & 3) * 16;
    const float4* wr = (const float4*)&Wp[mm * 64 + kg];
    float4 w0 = wr[0], w1 = wr[1], w2 = wr[2], w3 = wr[3];
    float wv[16] = {w0.x, w0.y, w0.z, w0.w, w1.x, w1.y, w1.z, w1.w,
                    w2.x, w2.y, w2.z, w2.w, w3.x, w3.y, w3.z, w3.w};
#pragma unroll
    for (int j = 0; j < 16; j++) wsh[kg + j][mm] = wv[j];
  }
  {
    int hh = tid >> 5, nn = tid & 31;
    int i = n0 + nn;
    float L = 0.f, o[8] = {};
#pragma unroll
    for (int p = 0; p < 8; p++) {
      size_t base = (size_t)((p * 8 + hh) * NPIX + i);
      L += pl[base];
      const float4 a0 = *(const float4*)&pacc[base * 8];
      const float4 a1 = *(const float4*)&pacc[base * 8 + 4];
      o[0] += a0.x; o[1] += a0.y; o[2] += a0.z; o[3] += a0.w;
      o[4] += a1.x; o[5] += a1.y; o[6] += a1.z; o[7] += a1.w;
    }
    float inv = 1.f / L;
#pragma unroll
    for (int d = 0; d < 8; d++) at[hh * 8 + d][nn] = o[d] * inv;
  }
  __syncthreads();
  int ty = tid >> 5, tx = tid & 31;
  float acc[8] = {};
#pragma unroll 8
  for (int k = 0; k < 64; k++) {
    float b = at[k][tx];
    float4 a0 = *(const float4*)&wsh[k][ty * 8];
    float4 a1 = *(const float4*)&wsh[k][ty * 8 + 4];
    acc[0] = fmaf(a0.x, b, acc[0]);
    acc[1] = fmaf(a0.y, b, acc[1]);
    acc[2] = fmaf(a0.z, b, acc[2]);
    acc[3] = fmaf(a0.w, b, acc[3]);
    acc[4] = fmaf(a1.x, b, acc[4]);
    acc[5] = fmaf(a1.y, b, acc[5]);
    acc[6] = fmaf(a1.z, b, acc[6]);
    acc[7] = fmaf(a1.w, b, acc[7]);
  }
  float v[8], sn = 0.f, qn = 0.f;
#pragma unroll
  for (int im = 0; im < 8; im++) {
    int row = ty * 8 + im;
    float vv = acc[im] + bp[row] + x[row * NPIX + n0 + tx];
    v[im] = vv;
    sn += vv;
    qn = fmaf(vv, vv, qn);
  }
  if (ch == 0) {
#pragma unroll
    for (int im = 0; im < 8; im++)
      x1[(ty * 8 + im) * NPIX + n0 + tx] = v[im];
  }
  ps[ty][tx] = sn;
  pq[ty][tx] = qn;
  __syncthreads();
  if (tid < 32) {
    float s = 0.f, q = 0.f;
#pragma unroll
    for (int t = 0; t < 8; t++) {
      s += ps[t][tid];
      q += pq[t][tid];
    }
    float mu = s * (1.f / 64.f);
    mus[tid] = mu;
    rss[tid] = rsqrtf(q * (1.f / 64.f) - mu * mu + 1e-5f);
  }
  __syncthreads();
  {
    float muv = mus[tx], rsv = rss[tx];
#pragma unroll
    for (int im = 0; im < 8; im++) {
      int row = ty * 8 + im;
      xsl[row][tx] = (v[im] - muv) * rsv * ln2w[row] + ln2b[row];
    }
  }
  {
    int mm = tid >> 2, kg = (tid & 3) * 16;
    const float4* wr = (const float4*)&W1[(ch * 64 + mm) * 64 + kg];
    float4 w0 = wr[0], w1 = wr[1], w2 = wr[2], w3 = wr[3];
    float wv[16] = {w0.x, w0.y, w0.z, w0.w, w1.x, w1.y, w1.z, w1.w,
                    w2.x, w2.y, w2.z, w2.w, w3.x, w3.y, w3.z, w3.w};
#pragma unroll
    for (int j = 0; j < 16; j++) wsh[kg + j][mm] = wv[j];
  }
  __syncthreads();
  float a2[8] = {};
#pragma unroll 8
  for (int k = 0; k < 64; k++) {
    float b = xsl[k][tx];
    float4 a0 = *(const float4*)&wsh[k][ty * 8];
    float4 a1 = *(const float4*)&wsh[k][ty * 8 + 4];
    a2[0] = fmaf(a0.x, b, a2[0]);
    a2[1] = fmaf(a0.y, b, a2[1]);
    a2[2] = fmaf(a0.z, b, a2[2]);
    a2[3] = fmaf(a0.w, b, a2[3]);
    a2[4] = fmaf(a1.x, b, a2[4]);
    a2[5] = fmaf(a1.y, b, a2[5]);
    a2[6] = fmaf(a1.z, b, a2[6]);
    a2[7] = fmaf(a1.w, b, a2[7]);
  }
#pragma unroll
  for (int im = 0; im < 8; im++) {
    int row = ch * 64 + ty * 8 + im;
    f1[row * NPIX + n0 + tx] = a2[im] + b1f[row];
  }
}

// ---------------------------------------------------------------------------
// Merged dw_gelu + ffn2: stage f2 = gelu(dw3x3(f1)) for this block's 32 px
// directly into LDS (zero recompute vs separate kernels; dw staged 2x for
// the two m-halves), then one-barrier GEMM + bias + residual.
// grid (128 n-tiles of 32 px (half-rows), 2 m-halves of 32).
__global__ __launch_bounds__(256) void ffn2_dw_kernel(
    const float* __restrict__ f1, const float* __restrict__ dww,
    const float* __restrict__ dwb, const float* __restrict__ W,
    const float* __restrict__ bias, const float* __restrict__ resid,
    float* __restrict__ C) {
  __shared__ float xs[256][36];   // f2 tile [k=ch][px], stride 36
  __shared__ float wsh[256][33];  // W [k][m], stride 33 (conflict-free)
  int n0 = blockIdx.x * 32, m0 = blockIdx.y * 32;
  int tid = threadIdx.x;
  int y = n0 >> 6, x0 = n0 & 63;
  // stage W: 32 rows x 256 k
#pragma unroll
  for (int e = tid; e < 8192; e += 256) {
    int mm = e >> 8, kk = e & 255;
    wsh[kk][mm] = W[(m0 + mm) * 256 + kk];
  }
  // stage f2 via dw+gelu: 8 iterations of (ch, 4 px)
  {
    int px4 = (tid & 7) * 4;
    int xabs = x0 + px4;
#pragma unroll
    for (int k = 0; k < 8; k++) {
      int c = (tid >> 3) + 32 * k;
      const float* base = f1 + c * NPIX;
      float wv[9];
#pragma unroll
      for (int i = 0; i < 9; i++) wv[i] = dww[c * 9 + i];
      float bc = dwb[c];
      float a[4] = {bc, bc, bc, bc};
#pragma unroll
      for (int dy = 0; dy < 3; dy++) {
        int yy = y + dy - 1;
        if (yy < 0 || yy > 63) continue;
        const float* row = base + yy * IMG + xabs;
        float4 mid = *(const float4*)row;
        float left = (xabs > 0) ? row[-1] : 0.f;
        float right = (xabs + 4 < IMG) ? row[4] : 0.f;
        float win[6] = {left, mid.x, mid.y, mid.z, mid.w, right};
#pragma unroll
        for (int o = 0; o < 4; o++)
#pragma unroll
          for (int dx = 0; dx < 3; dx++)
            a[o] = fmaf(wv[dy * 3 + dx], win[o + dx], a[o]);
      }
      float4 o4;
      float* op = &o4.x;
#pragma unroll
      for (int o = 0; o < 4; o++)
        op[o] = 0.5f * a[o] * (1.f + erff(a[o] * 0.70710678118654752f));
      *(float4*)&xs[c][px4] = o4;
    }
  }
  __syncthreads();
  int m2 = (tid >> 4) * 2, np = (tid & 15) * 2;
  float a00 = 0.f, a01 = 0.f, a10 = 0.f, a11 = 0.f;
#pragma unroll 8
  for (int kk = 0; kk < 256; kk++) {
    float w0 = wsh[kk][m2];
    float w1 = wsh[kk][m2 + 1];
    float b0 = xs[kk][np];
    float b1 = xs[kk][np + 1];
    a00 = fmaf(w0, b0, a00);
    a01 = fmaf(w0, b1, a01);
    a10 = fmaf(w1, b0, a10);
    a11 = fmaf(w1, b1, a11);
  }
  int r0 = m0 + m2, r1 = r0 + 1;
  float bv0 = bias[r0], bv1 = bias[r1];
  const float2 rr0 = *(const float2*)&resid[r0 * NPIX + n0 + np];
  const float2 rr1 = *(const float2*)&resid[r1 * NPIX + n0 + np];
  *(float2*)&C[r0 * NPIX + n0 + np] =
      make_float2(a00 + bv0 + rr0.x, a01 + bv0 + rr0.y);
  *(float2*)&C[r1 * NPIX + n0 + np] =
      make_float2(a10 + bv1 + rr1.x, a11 + bv1 + rr1.y);
}

// ---------------------------------------------------------------------------
extern "C" void kernel_launch(void* const* d_in, const int* in_sizes, int n_in,
                              void* d_out, int out_size, void* d_ws,
                              size_t ws_size, hipStream_t stream) {
  const float* x      = (const float*)d_in[0];
  const float* luma   = (const float*)d_in[1];
  const float* ln1_w  = (const float*)d_in[2];
  const float* ln1_b  = (const float*)d_in[3];
  const float* qkv_w  = (const float*)d_in[4];
  const float* qkv_b  = (const float*)d_in[5];
  const float* proj_w = (const float*)d_in[6];
  const float* proj_b = (const float*)d_in[7];
  const float* lc1_w  = (const float*)d_in[8];
  const float* lc1_b  = (const float*)d_in[9];
  const float* lc2_w  = (const float*)d_in[10];
  const float* lc2_b  = (const float*)d_in[11];
  const float* gam_w  = (const float*)d_in[12];
  const float* gam_b  = (const float*)d_in[13];
  const float* bet_w  = (const float*)d_in[14];
  const float* bet_b  = (const float*)d_in[15];
  const float* alpha  = (const float*)d_in[16];
  const float* ln2_w  = (const float*)d_in[17];
  const float* ln2_b  = (const float*)d_in[18];
  const float* ffn1_w = (const float*)d_in[19];
  const float* ffn1_b = (const float*)d_in[20];
  const float* dw_w   = (const float*)d_in[21];
  const float* dw_b   = (const float*)d_in[22];
  const float* ffn2_w = (const float*)d_in[23];
  const float* ffn2_b = (const float*)d_in[24];
  float* out = (float*)d_out;

  float* w = (float*)d_ws;
  float* pooled = w + 0;        // 4096
  float* bsums  = w + 4096;     // 64 (16 used)
  unsigned short* cbuf = (unsigned short*)(w + 4160);     // 64 f (16 us used)
  float* mu1 = w + 4224;        // 4096
  float* rs1 = w + 8320;        // 4096
  unsigned short* qhl  = (unsigned short*)(w + 12416);    // 262144 f
  unsigned short* khl  = (unsigned short*)(w + 274560);   // 262144 f
  unsigned short* vthx = (unsigned short*)(w + 536704);   // 131072 f
  unsigned short* vtlx = (unsigned short*)(w + 667776);   // 131072 f
  float* pacc = w + 798848;    // 2097152 (JP=8)
  float* pl   = w + 2896000;   // 262144
  float* x1   = w + 3158144;   // 262144
  float* f1   = w + 3420288;   // 1048576
  float* h2   = w + 4468864;   // 131072

  lc12_kernel<<<dim3(16, 8), 256, 0, stream>>>(luma, lc1_w, lc1_b, lc2_w,
                                               lc2_b, x, h2, pooled, bsums,
                                               mu1, rs1, cbuf);
  ln_qkv_kernel<<<dim3(128, 3), 256, 0, stream>>>(
      x, mu1, rs1, ln1_w, ln1_b, qkv_w, qkv_b, gam_w, gam_b, bet_w, bet_b, h2,
      pooled, bsums, alpha, qhl, khl, vthx, vtlx);
  attn_kernel<<<dim3(16, 8, 8), 256, 0, stream>>>(qhl, khl, vthx, vtlx, cbuf,
                                                  pacc, pl);
  proj_ffn1_kernel<<<dim3(128, 4), 256, 0, stream>>>(
      pacc, pl, proj_w, proj_b, x, ln2_w, ln2_b, ffn1_w, ffn1_b, x1, f1);
  ffn2_dw_kernel<<<dim3(128, 2), 256, 0, stream>>>(f1, dw_w, dw_b, ffn2_w,
                                                   ffn2_b, x1, out);
}

// Round 13
// 194.067 us; speedup vs baseline: 1.0608x; 1.0093x over previous
//
#include <hip/hip_runtime.h>
#include <math.h>

// B=1, C=64, H=W=64, N=4096, heads=8, dh=8, inner=64, hid_lc=32, hid_f=256.
#define NPIX 4096
#define IMG 64

typedef __attribute__((ext_vector_type(8))) short bf16x8;
typedef __attribute__((ext_vector_type(4))) float floatx4;
typedef __attribute__((ext_vector_type(4))) unsigned int uintx4;

// fp32 -> (hi bf16 in low16) | (lo bf16 in high16), lo = x - f32(hi)
__device__ __forceinline__ unsigned int split_pack(float x) {
  unsigned int u = __float_as_uint(x);
  unsigned int hif = u & 0xffff0000u;
  float lof = x - __uint_as_float(hif);
  return (u >> 16) | (__float_as_uint(lof) & 0xffff0000u);
}

// pack hi16 of two floats: low16 = hi16(a), high16 = hi16(b)
__device__ __forceinline__ unsigned int hi_pair(float a, float b) {
  return (__float_as_uint(a) >> 16) | (__float_as_uint(b) & 0xffff0000u);
}

// ---------------------------------------------------------------------------
// Merged lc1+lc2 (unchanged from r12): stage 20x20 luma halo, h1 halo in LDS,
// lc2 conv -> h2; ocg==0 also emits pooled/bsums/LN1 stats; (0,0) inits cbuf.
__global__ __launch_bounds__(256) void lc12_kernel(
    const float* __restrict__ luma, const float* __restrict__ w1,
    const float* __restrict__ b1, const float* __restrict__ w2,
    const float* __restrict__ b2, const float* __restrict__ x,
    float* __restrict__ h2, float* __restrict__ pooled,
    float* __restrict__ bsums, float* __restrict__ mu1,
    float* __restrict__ rs1, unsigned short* __restrict__ cbuf) {
  __shared__ float lum[400];      // 20x20
  __shared__ float sw1[288];      // lc1 weights 32x9
  __shared__ float tin[32][324];  // h1 on 18x18 halo per ic
  __shared__ float swt[4][32][9];
  __shared__ float red[256];
  int tile = blockIdx.x, ocg = blockIdx.y;
  int ty0 = (tile >> 2) * 16, tx0 = (tile & 3) * 16;
  int tid = threadIdx.x;
  if (tile == 0 && ocg == 0 && tid < 16) cbuf[tid] = (tid < 8) ? 0x3F80 : 0;
  for (int idx = tid; idx < 400; idx += 256) {
    int py = idx / 20, px = idx - py * 20;
    int gy = ty0 + py - 2, gx = tx0 + px - 2;
    lum[idx] = (gy >= 0 && gy < IMG && gx >= 0 && gx < IMG)
                   ? luma[gy * IMG + gx]
                   : 0.f;
  }
  for (int idx = tid; idx < 288; idx += 256) sw1[idx] = w1[idx];
  for (int idx = tid; idx < 1152; idx += 256) {
    int o = idx / 288, r = idx - o * 288;
    swt[o][r / 9][r % 9] = w2[(ocg * 4 + o) * 288 + r];
  }
  __syncthreads();
  for (int idx = tid; idx < 32 * 324; idx += 256) {
    int ic = idx / 324, pos = idx - ic * 324;
    int py = pos / 18, px = pos - py * 18;
    int gy = ty0 + py - 1, gx = tx0 + px - 1;
    float v = 0.f;
    if (gy >= 0 && gy < IMG && gx >= 0 && gx < IMG) {
      float s = b1[ic];
      const float* wp = &sw1[ic * 9];
#pragma unroll
      for (int dy = 0; dy < 3; dy++)
#pragma unroll
        for (int dx = 0; dx < 3; dx++)
          s = fmaf(wp[dy * 3 + dx], lum[(py + dy) * 20 + px + dx], s);
      v = fmaxf(s, 0.f);
    }
    tin[ic][pos] = v;
  }
  __syncthreads();
  int ly = tid >> 4, lx = tid & 15;
  int p = (ty0 + ly) * IMG + tx0 + lx;
  float acc[4];
#pragma unroll
  for (int o = 0; o < 4; o++) acc[o] = b2[ocg * 4 + o];
  for (int ic = 0; ic < 32; ic++) {
    float v[9];
#pragma unroll
    for (int dy = 0; dy < 3; dy++)
#pragma unroll
      for (int dx = 0; dx < 3; dx++)
        v[dy * 3 + dx] = tin[ic][(ly + dy) * 18 + lx + dx];
#pragma unroll
    for (int o = 0; o < 4; o++)
#pragma unroll
      for (int t = 0; t < 9; t++) acc[o] = fmaf(swt[o][ic][t], v[t], acc[o]);
  }
#pragma unroll
  for (int o = 0; o < 4; o++)
    h2[(ocg * 4 + o) * NPIX + p] = fmaxf(acc[o], 0.f);
  if (ocg == 0) {
    int gy = ty0 + ly, gx = tx0 + lx;
    float sv = 0.f;
#pragma unroll
    for (int dy = 0; dy < 3; dy++)
#pragma unroll
      for (int dx = 0; dx < 3; dx++)
        sv += lum[(ly + dy + 1) * 20 + lx + dx + 1];
    float cy = 3.f - (gy == 0 ? 1.f : 0.f) - (gy == 63 ? 1.f : 0.f);
    float cx = 3.f - (gx == 0 ? 1.f : 0.f) - (gx == 63 ? 1.f : 0.f);
    float pv = (cy * cx - sv) * (1.f / 9.f);
    pooled[p] = pv;
    red[tid] = pv;
    __syncthreads();
    for (int st = 128; st > 0; st >>= 1) {
      if (tid < st) red[tid] += red[tid + st];
      __syncthreads();
    }
    if (tid == 0) bsums[tile] = red[0];
    float s = 0.f, q = 0.f;
#pragma unroll 8
    for (int cc = 0; cc < 64; cc++) {
      float xv = x[cc * NPIX + p];
      s += xv;
      q = fmaf(xv, xv, q);
    }
    float mu = s * (1.f / 64.f);
    mu1[p] = mu;
    rs1[p] = rsqrtf(q * (1.f / 64.f) - mu * mu + 1e-5f);
  }
}

// ---------------------------------------------------------------------------
// Fused per-pixel LN (precomputed stats) + qkv 1x1 GEMM + gam/bet in-register
// + modulation + hi/lo split store. grid (128, 3). (unchanged from r12)
__global__ __launch_bounds__(256) void ln_qkv_kernel(
    const float* __restrict__ X, const float* __restrict__ mu1,
    const float* __restrict__ rs1, const float* __restrict__ lnw,
    const float* __restrict__ lnb, const float* __restrict__ W,
    const float* __restrict__ bias, const float* __restrict__ gamW,
    const float* __restrict__ gamB, const float* __restrict__ betW,
    const float* __restrict__ betB, const float* __restrict__ h2,
    const float* __restrict__ pooled, const float* __restrict__ bsums,
    const float* __restrict__ alpha, unsigned short* __restrict__ qhl,
    unsigned short* __restrict__ khl, unsigned short* __restrict__ vthx,
    unsigned short* __restrict__ vtlx) {
  const float QSCALE = 0.35355339059327376f * 1.4426950408889634f;
  __shared__ float xs[64][32];
  __shared__ float wsh[64][64];
  __shared__ float h2s[32][32];
  __shared__ float wgs[32][64];
  __shared__ float wbs[32][64];
  __shared__ float mu[32];
  __shared__ float rs[32];
  int n0 = blockIdx.x * 32, part = blockIdx.y, m0 = part * 64;
  int tid = threadIdx.x;
  if (tid < 32) {
    mu[tid] = mu1[n0 + tid];
    rs[tid] = rs1[n0 + tid];
  }
  {
    int e = tid * 2;
    int c = e >> 3, off = (e & 7) * 4;
    *(float4*)&xs[c][off] = *(const float4*)&X[c * NPIX + n0 + off];
    int e1 = e + 1;
    int c1 = e1 >> 3, off1 = (e1 & 7) * 4;
    *(float4*)&xs[c1][off1] = *(const float4*)&X[c1 * NPIX + n0 + off1];
  }
  {
    int m = tid >> 2, kg = (tid & 3) * 16;
    const float4* wr = (const float4*)&W[(m0 + m) * 64 + kg];
    float4 w0 = wr[0], w1 = wr[1], w2 = wr[2], w3 = wr[3];
    float wv[16] = {w0.x, w0.y, w0.z, w0.w, w1.x, w1.y, w1.z, w1.w,
                    w2.x, w2.y, w2.z, w2.w, w3.x, w3.y, w3.z, w3.w};
#pragma unroll
    for (int j = 0; j < 16; j++) wsh[kg + j][m] = wv[j];
  }
  {
    int k = tid >> 3, nf = (tid & 7) * 4;
    *(float4*)&h2s[k][nf] = *(const float4*)&h2[k * NPIX + n0 + nf];
  }
  {
    int m = tid >> 2, kg = (tid & 3) * 8;
    const float4* g0 = (const float4*)&gamW[m * 32 + kg];
    float4 a = g0[0], b4 = g0[1];
    float gv[8] = {a.x, a.y, a.z, a.w, b4.x, b4.y, b4.z, b4.w};
#pragma unroll
    for (int j = 0; j < 8; j++) wgs[kg + j][m] = gv[j];
    const float4* bb0 = (const float4*)&betW[m * 32 + kg];
    float4 c4 = bb0[0], d4 = bb0[1];
    float bv[8] = {c4.x, c4.y, c4.z, c4.w, d4.x, d4.y, d4.z, d4.w};
#pragma unroll
    for (int j = 0; j < 8; j++) wbs[kg + j][m] = bv[j];
  }
  __syncthreads();
  {
    int c = tid >> 2, pg = (tid & 3) * 8;
    float wc = lnw[c], bc = lnb[c];
#pragma unroll
    for (int j = 0; j < 8; j++) {
      int p = pg + j;
      xs[c][p] = (xs[c][p] - mu[p]) * rs[p] * wc + bc;
    }
  }
  __syncthreads();
  int tx = tid & 15, ty = tid >> 4;
  float ga[4][2] = {}, ba[4][2] = {};
#pragma unroll 8
  for (int kk = 0; kk < 32; kk++) {
    float4 wg4 = *(const float4*)&wgs[kk][ty * 4];
    float4 wb4 = *(const float4*)&wbs[kk][ty * 4];
    float2 h22 = *(const float2*)&h2s[kk][tx * 2];
    float gv[4] = {wg4.x, wg4.y, wg4.z, wg4.w};
    float bv[4] = {wb4.x, wb4.y, wb4.z, wb4.w};
    float hv[2] = {h22.x, h22.y};
#pragma unroll
    for (int im = 0; im < 4; im++)
#pragma unroll
      for (int in = 0; in < 2; in++) {
        ga[im][in] = fmaf(gv[im], hv[in], ga[im][in]);
        ba[im][in] = fmaf(bv[im], hv[in], ba[im][in]);
      }
  }
#pragma unroll
  for (int im = 0; im < 4; im++) {
    int cc = ty * 4 + im;
    float gb = gamB[cc], bb2 = betB[cc];
#pragma unroll
    for (int in = 0; in < 2; in++) {
      ga[im][in] += gb;
      ba[im][in] += bb2;
    }
  }
  float acc[4][2] = {};
#pragma unroll 8
  for (int kk = 0; kk < 64; kk++) {
    float4 a = *(const float4*)&wsh[kk][ty * 4];
    float2 b2 = *(const float2*)&xs[kk][tx * 2];
    float av[4] = {a.x, a.y, a.z, a.w};
    float bv[2] = {b2.x, b2.y};
#pragma unroll
    for (int im = 0; im < 4; im++)
#pragma unroll
      for (int in = 0; in < 2; in++)
        acc[im][in] = fmaf(av[im], bv[in], acc[im][in]);
  }
  float val[4][2];
#pragma unroll
  for (int im = 0; im < 4; im++) {
    int cc = ty * 4 + im;
    float bv = bias[m0 + cc];
#pragma unroll
    for (int in = 0; in < 2; in++)
      val[im][in] = fmaf(ga[im][in], acc[im][in] + bv, ba[im][in]);
  }
  if (part == 0) {
    float msum = 0.f;
#pragma unroll
    for (int t = 0; t < 16; t++) msum += bsums[t];
    float mean = msum * (1.f / 4096.f);
    float a0 = alpha[0];
    const float2 pv = *(const float2*)&pooled[n0 + tx * 2];
    float iv[2] = {a0 * (pv.x - mean), a0 * (pv.y - mean)};
#pragma unroll
    for (int im = 0; im < 4; im++)
#pragma unroll
      for (int in = 0; in < 2; in++)
        val[im][in] = (val[im][in] + iv[in]) * QSCALE;
  }
  if (part < 2) {
    unsigned short* dst = (part == 0) ? qhl : khl;
    int h = ty >> 1, d0 = (ty & 1) * 4;
#pragma unroll
    for (int in = 0; in < 2; in++) {
      int n = n0 + tx * 2 + in;
      unsigned int pk[4];
#pragma unroll
      for (int im = 0; im < 4; im++) pk[im] = split_pack(val[im][in]);
      short4 hi, lo;
      hi.x = (short)(pk[0] & 0xffffu); hi.y = (short)(pk[1] & 0xffffu);
      hi.z = (short)(pk[2] & 0xffffu); hi.w = (short)(pk[3] & 0xffffu);
      lo.x = (short)(pk[0] >> 16); lo.y = (short)(pk[1] >> 16);
      lo.z = (short)(pk[2] >> 16); lo.w = (short)(pk[3] >> 16);
      unsigned short* base = dst + ((size_t)(h * NPIX + n) << 4) + d0;
      *(short4*)base = hi;
      *(short4*)(base + 8) = lo;
    }
  } else {
    int nq = n0 + tx * 2;
    int off0 = (nq >> 5) * 32 + ((nq >> 4) & 1) * 4 + ((nq >> 2) & 3) * 8 +
               (nq & 3);
#pragma unroll
    for (int im = 0; im < 4; im++) {
      int cc = ty * 4 + im;
      unsigned int pk0 = split_pack(val[im][0]);
      unsigned int pk1 = split_pack(val[im][1]);
      short2 hi, lo;
      hi.x = (short)(pk0 & 0xffffu);
      hi.y = (short)(pk1 & 0xffffu);
      lo.x = (short)(pk0 >> 16);
      lo.y = (short)(pk1 >> 16);
      *(short2*)(vthx + (size_t)cc * NPIX + off0) = hi;
      *(short2*)(vtlx + (size_t)cc * NPIX + off0) = lo;
    }
  }
}

// ---------------------------------------------------------------------------
// MFMA flash attention: 4 i-tiles/wave, JP=8, zero LDS. Unroll 4 for deeper
// load pipelining. grid (16 i-tiles of 256, 8 heads, 8 jp).
__global__ __launch_bounds__(256, 4) void attn_kernel(
    const unsigned short* __restrict__ qhl,
    const unsigned short* __restrict__ khl,
    const unsigned short* __restrict__ vthx,
    const unsigned short* __restrict__ vtlx,
    const unsigned short* __restrict__ cbuf, float* __restrict__ pacc,
    float* __restrict__ pl) {
  int tid = threadIdx.x;
  int wave = tid >> 6, lane = tid & 63;
  int g = lane >> 4, c = lane & 15;
  int h = blockIdx.y, jp = blockIdx.z;
  int i0 = blockIdx.x * 256 + wave * 64;
  int jbase = jp * 512;
  bf16x8 qB[4];
#pragma unroll
  for (int t = 0; t < 4; t++)
    qB[t] = *(const bf16x8*)(qhl + ((size_t)(h * NPIX + i0 + t * 16 + c) << 4) +
                             ((g & 1) << 3));
  const unsigned short* kp =
      khl + ((size_t)(h * NPIX + jbase + c) << 4) + ((g >> 1) << 3);
  const unsigned short* vhp;
  const unsigned short* vlp;
  int vstep;
  if (c < 8) {
    vhp = vthx + (size_t)(h * 8 + c) * NPIX + jbase + (g << 3);
    vlp = vtlx + (size_t)(h * 8 + c) * NPIX + jbase + (g << 3);
    vstep = 32;
  } else {
    vhp = (c == 8) ? cbuf : (cbuf + 8);  // ones row / zero rows
    vlp = cbuf + 8;
    vstep = 0;
  }
  floatx4 zero4 = {0.f, 0.f, 0.f, 0.f};
  floatx4 aH[4], aM[4];
#pragma unroll
  for (int t = 0; t < 4; t++) {
    aH[t] = zero4;
    aM[t] = zero4;
  }
#pragma unroll 4
  for (int jt = 0; jt < 16; ++jt) {
    bf16x8 ka0 = *(const bf16x8*)kp;
    bf16x8 ka1 = *(const bf16x8*)(kp + 256);
    bf16x8 avh = *(const bf16x8*)vhp;
    bf16x8 avl = *(const bf16x8*)vlp;
    kp += 512;
    vhp += vstep;
    vlp += vstep;
#pragma unroll
    for (int t = 0; t < 4; t++) {
      floatx4 s0 =
          __builtin_amdgcn_mfma_f32_16x16x32_bf16(ka0, qB[t], zero4, 0, 0, 0);
      floatx4 s1 =
          __builtin_amdgcn_mfma_f32_16x16x32_bf16(ka1, qB[t], zero4, 0, 0, 0);
      float p0 = __builtin_amdgcn_exp2f(fminf(s0[0], 80.f));
      float p1 = __builtin_amdgcn_exp2f(fminf(s0[1], 80.f));
      float p2 = __builtin_amdgcn_exp2f(fminf(s0[2], 80.f));
      float p3 = __builtin_amdgcn_exp2f(fminf(s0[3], 80.f));
      float p4 = __builtin_amdgcn_exp2f(fminf(s1[0], 80.f));
      float p5 = __builtin_amdgcn_exp2f(fminf(s1[1], 80.f));
      float p6 = __builtin_amdgcn_exp2f(fminf(s1[2], 80.f));
      float p7 = __builtin_amdgcn_exp2f(fminf(s1[3], 80.f));
      uintx4 bh;
      bh.x = hi_pair(p0, p1);
      bh.y = hi_pair(p2, p3);
      bh.z = hi_pair(p4, p5);
      bh.w = hi_pair(p6, p7);
      bf16x8 pbh = __builtin_bit_cast(bf16x8, bh);
      aH[t] = __builtin_amdgcn_mfma_f32_16x16x32_bf16(avh, pbh, aH[t], 0, 0, 0);
      aM[t] = __builtin_amdgcn_mfma_f32_16x16x32_bf16(avl, pbh, aM[t], 0, 0, 0);
    }
  }
#pragma unroll
  for (int t = 0; t < 4; t++) {
    floatx4 o = aH[t] + aM[t];
    if (g < 2) {
      size_t b0 = (size_t)((jp * 8 + h) * NPIX + i0 + t * 16 + c);
      *(float4*)&pacc[b0 * 8 + g * 4] = make_float4(o[0], o[1], o[2], o[3]);
    } else if (g == 2) {
      pl[(size_t)((jp * 8 + h) * NPIX + i0 + t * 16 + c)] = o[0];
    }
  }
}

// ---------------------------------------------------------------------------
// Fused: combine 8 j-partitions -> proj GEMM + residual -> x1 (ch==0) + LN2
// stats -> LN -> one 64-ch slice of ffn1 -> f1. grid (128, 4). (unchanged)
__global__ __launch_bounds__(256) void proj_ffn1_kernel(
    const float* __restrict__ pacc, const float* __restrict__ pl,
    const float* __restrict__ Wp, const float* __restrict__ bp,
    const float* __restrict__ x, const float* __restrict__ ln2w,
    const float* __restrict__ ln2b, const float* __restrict__ W1,
    const float* __restrict__ b1f, float* __restrict__ x1,
    float* __restrict__ f1) {
  __shared__ float at[64][33];
  __shared__ float wsh[64][64];
  __shared__ float xsl[64][33];
  __shared__ float ps[8][33];
  __shared__ float pq[8][33];
  __shared__ float mus[32];
  __shared__ float rss[32];
  int n0 = blockIdx.x * 32;
  int ch = blockIdx.y;
  int tid = threadIdx.x;
  {
    int mm = tid >> 2, kg = (tid & 3) * 16;
    const float4* wr = (const float4*)&Wp[mm * 64 + kg];
    float4 w0 = wr[0], w1 = wr[1], w2 = wr[2], w3 = wr[3];
    float wv[16] = {w0.x, w0.y, w0.z, w0.w, w1.x, w1.y, w1.z, w1.w,
                    w2.x, w2.y, w2.z, w2.w, w3.x, w3.y, w3.z, w3.w};
#pragma unroll
    for (int j = 0; j < 16; j++) wsh[kg + j][mm] = wv[j];
  }
  {
    int hh = tid >> 5, nn = tid & 31;
    int i = n0 + nn;
    float L = 0.f, o[8] = {};
#pragma unroll
    for (int p = 0; p < 8; p++) {
      size_t base = (size_t)((p * 8 + hh) * NPIX + i);
      L += pl[base];
      const float4 a0 = *(const float4*)&pacc[base * 8];
      const float4 a1 = *(const float4*)&pacc[base * 8 + 4];
      o[0] += a0.x; o[1] += a0.y; o[2] += a0.z; o[3] += a0.w;
      o[4] += a1.x; o[5] += a1.y; o[6] += a1.z; o[7] += a1.w;
    }
    float inv = 1.f / L;
#pragma unroll
    for (int d = 0; d < 8; d++) at[hh * 8 + d][nn] = o[d] * inv;
  }
  __syncthreads();
  int ty = tid >> 5, tx = tid & 31;
  float acc[8] = {};
#pragma unroll 8
  for (int k = 0; k < 64; k++) {
    float b = at[k][tx];
    float4 a0 = *(const float4*)&wsh[k][ty * 8];
    float4 a1 = *(const float4*)&wsh[k][ty * 8 + 4];
    acc[0] = fmaf(a0.x, b, acc[0]);
    acc[1] = fmaf(a0.y, b, acc[1]);
    acc[2] = fmaf(a0.z, b, acc[2]);
    acc[3] = fmaf(a0.w, b, acc[3]);
    acc[4] = fmaf(a1.x, b, acc[4]);
    acc[5] = fmaf(a1.y, b, acc[5]);
    acc[6] = fmaf(a1.z, b, acc[6]);
    acc[7] = fmaf(a1.w, b, acc[7]);
  }
  float v[8], sn = 0.f, qn = 0.f;
#pragma unroll
  for (int im = 0; im < 8; im++) {
    int row = ty * 8 + im;
    float vv = acc[im] + bp[row] + x[row * NPIX + n0 + tx];
    v[im] = vv;
    sn += vv;
    qn = fmaf(vv, vv, qn);
  }
  if (ch == 0) {
#pragma unroll
    for (int im = 0; im < 8; im++)
      x1[(ty * 8 + im) * NPIX + n0 + tx] = v[im];
  }
  ps[ty][tx] = sn;
  pq[ty][tx] = qn;
  __syncthreads();
  if (tid < 32) {
    float s = 0.f, q = 0.f;
#pragma unroll
    for (int t = 0; t < 8; t++) {
      s += ps[t][tid];
      q += pq[t][tid];
    }
    float mu = s * (1.f / 64.f);
    mus[tid] = mu;
    rss[tid] = rsqrtf(q * (1.f / 64.f) - mu * mu + 1e-5f);
  }
  __syncthreads();
  {
    float muv = mus[tx], rsv = rss[tx];
#pragma unroll
    for (int im = 0; im < 8; im++) {
      int row = ty * 8 + im;
      xsl[row][tx] = (v[im] - muv) * rsv * ln2w[row] + ln2b[row];
    }
  }
  {
    int mm = tid >> 2, kg = (tid & 3) * 16;
    const float4* wr = (const float4*)&W1[(ch * 64 + mm) * 64 + kg];
    float4 w0 = wr[0], w1 = wr[1], w2 = wr[2], w3 = wr[3];
    float wv[16] = {w0.x, w0.y, w0.z, w0.w, w1.x, w1.y, w1.z, w1.w,
                    w2.x, w2.y, w2.z, w2.w, w3.x, w3.y, w3.z, w3.w};
#pragma unroll
    for (int j = 0; j < 16; j++) wsh[kg + j][mm] = wv[j];
  }
  __syncthreads();
  float a2[8] = {};
#pragma unroll 8
  for (int k = 0; k < 64; k++) {
    float b = xsl[k][tx];
    float4 a0 = *(const float4*)&wsh[k][ty * 8];
    float4 a1 = *(const float4*)&wsh[k][ty * 8 + 4];
    a2[0] = fmaf(a0.x, b, a2[0]);
    a2[1] = fmaf(a0.y, b, a2[1]);
    a2[2] = fmaf(a0.z, b, a2[2]);
    a2[3] = fmaf(a0.w, b, a2[3]);
    a2[4] = fmaf(a1.x, b, a2[4]);
    a2[5] = fmaf(a1.y, b, a2[5]);
    a2[6] = fmaf(a1.z, b, a2[6]);
    a2[7] = fmaf(a1.w, b, a2[7]);
  }
#pragma unroll
  for (int im = 0; im < 8; im++) {
    int row = ch * 64 + ty * 8 + im;
    f1[row * NPIX + n0 + tx] = a2[im] + b1f[row];
  }
}

// ---------------------------------------------------------------------------
// Merged dw_gelu + ffn2, 16-px tiles for 2 blocks/CU: stage f2 =
// gelu(dw3x3(f1)) for 16 px into LDS, then one-barrier GEMM + bias + resid.
// grid (256 n-tiles of 16 px, 2 m-halves of 32).
__global__ __launch_bounds__(256) void ffn2_dw_kernel(
    const float* __restrict__ f1, const float* __restrict__ dww,
    const float* __restrict__ dwb, const float* __restrict__ W,
    const float* __restrict__ bias, const float* __restrict__ resid,
    float* __restrict__ C) {
  __shared__ float xs[256][20];   // f2 tile [k=ch][px], stride 20
  __shared__ float wsh[256][33];  // W [k][m], stride 33
  int n0 = blockIdx.x * 16, m0 = blockIdx.y * 32;
  int tid = threadIdx.x;
  int y = n0 >> 6, x0 = n0 & 63;
#pragma unroll
  for (int e = tid; e < 8192; e += 256) {
    int mm = e >> 8, kk = e & 255;
    wsh[kk][mm] = W[(m0 + mm) * 256 + kk];
  }
  {
    int px4 = (tid & 3) * 4;
    int xabs = x0 + px4;
#pragma unroll
    for (int k = 0; k < 4; k++) {
      int c = (tid >> 2) + 64 * k;
      const float* base = f1 + c * NPIX;
      float wv[9];
#pragma unroll
      for (int i = 0; i < 9; i++) wv[i] = dww[c * 9 + i];
      float bc = dwb[c];
      float a[4] = {bc, bc, bc, bc};
#pragma unroll
      for (int dy = 0; dy < 3; dy++) {
        int yy = y + dy - 1;
        if (yy < 0 || yy > 63) continue;
        const float* row = base + yy * IMG + xabs;
        float4 mid = *(const float4*)row;
        float left = (xabs > 0) ? row[-1] : 0.f;
        float right = (xabs + 4 < IMG) ? row[4] : 0.f;
        float win[6] = {left, mid.x, mid.y, mid.z, mid.w, right};
#pragma unroll
        for (int o = 0; o < 4; o++)
#pragma unroll
          for (int dx = 0; dx < 3; dx++)
            a[o] = fmaf(wv[dy * 3 + dx], win[o + dx], a[o]);
      }
      float4 o4;
      float* op = &o4.x;
#pragma unroll
      for (int o = 0; o < 4; o++)
        op[o] = 0.5f * a[o] * (1.f + erff(a[o] * 0.70710678118654752f));
      *(float4*)&xs[c][px4] = o4;
    }
  }
  __syncthreads();
  int m = tid >> 3, np = (tid & 7) * 2;
  float a0 = 0.f, a1 = 0.f;
#pragma unroll 8
  for (int kk = 0; kk < 256; kk++) {
    float w0 = wsh[kk][m];
    float b0 = xs[kk][np];
    float b1 = xs[kk][np + 1];
    a0 = fmaf(w0, b0, a0);
    a1 = fmaf(w0, b1, a1);
  }
  int row = m0 + m;
  float bv = bias[row];
  const float2 rr = *(const float2*)&resid[row * NPIX + n0 + np];
  *(float2*)&C[row * NPIX + n0 + np] =
      make_float2(a0 + bv + rr.x, a1 + bv + rr.y);
}

// ---------------------------------------------------------------------------
extern "C" void kernel_launch(void* const* d_in, const int* in_sizes, int n_in,
                              void* d_out, int out_size, void* d_ws,
                              size_t ws_size, hipStream_t stream) {
  const float* x      = (const float*)d_in[0];
  const float* luma   = (const float*)d_in[1];
  const float* ln1_w  = (const float*)d_in[2];
  const float* ln1_b  = (const float*)d_in[3];
  const float* qkv_w  = (const float*)d_in[4];
  const float* qkv_b  = (const float*)d_in[5];
  const float* proj_w = (const float*)d_in[6];
  const float* proj_b = (const float*)d_in[7];
  const float* lc1_w  = (const float*)d_in[8];
  const float* lc1_b  = (const float*)d_in[9];
  const float* lc2_w  = (const float*)d_in[10];
  const float* lc2_b  = (const float*)d_in[11];
  const float* gam_w  = (const float*)d_in[12];
  const float* gam_b  = (const float*)d_in[13];
  const float* bet_w  = (const float*)d_in[14];
  const float* bet_b  = (const float*)d_in[15];
  const float* alpha  = (const float*)d_in[16];
  const float* ln2_w  = (const float*)d_in[17];
  const float* ln2_b  = (const float*)d_in[18];
  const float* ffn1_w = (const float*)d_in[19];
  const float* ffn1_b = (const float*)d_in[20];
  const float* dw_w   = (const float*)d_in[21];
  const float* dw_b   = (const float*)d_in[22];
  const float* ffn2_w = (const float*)d_in[23];
  const float* ffn2_b = (const float*)d_in[24];
  float* out = (float*)d_out;

  float* w = (float*)d_ws;
  float* pooled = w + 0;        // 4096
  float* bsums  = w + 4096;     // 64 (16 used)
  unsigned short* cbuf = (unsigned short*)(w + 4160);     // 64 f (16 us used)
  float* mu1 = w + 4224;        // 4096
  float* rs1 = w + 8320;        // 4096
  unsigned short* qhl  = (unsigned short*)(w + 12416);    // 262144 f
  unsigned short* khl  = (unsigned short*)(w + 274560);   // 262144 f
  unsigned short* vthx = (unsigned short*)(w + 536704);   // 131072 f
  unsigned short* vtlx = (unsigned short*)(w + 667776);   // 131072 f
  float* pacc = w + 798848;    // 2097152 (JP=8)
  float* pl   = w + 2896000;   // 262144
  float* x1   = w + 3158144;   // 262144
  float* f1   = w + 3420288;   // 1048576
  float* h2   = w + 4468864;   // 131072

  lc12_kernel<<<dim3(16, 8), 256, 0, stream>>>(luma, lc1_w, lc1_b, lc2_w,
                                               lc2_b, x, h2, pooled, bsums,
                                               mu1, rs1, cbuf);
  ln_qkv_kernel<<<dim3(128, 3), 256, 0, stream>>>(
      x, mu1, rs1, ln1_w, ln1_b, qkv_w, qkv_b, gam_w, gam_b, bet_w, bet_b, h2,
      pooled, bsums, alpha, qhl, khl, vthx, vtlx);
  attn_kernel<<<dim3(16, 8, 8), 256, 0, stream>>>(qhl, khl, vthx, vtlx, cbuf,
                                                  pacc, pl);
  proj_ffn1_kernel<<<dim3(128, 4), 256, 0, stream>>>(
      pacc, pl, proj_w, proj_b, x, ln2_w, ln2_b, ffn1_w, ffn1_b, x1, f1);
  ffn2_dw_kernel<<<dim3(256, 2), 256, 0, stream>>>(f1, dw_w, dw_b, ffn2_w,
                                                   ffn2_b, x1, out);
}

// Round 14
// 193.942 us; speedup vs baseline: 1.0615x; 1.0006x over previous
//
#include <hip/hip_runtime.h>
#include <math.h>

// B=1, C=64, H=W=64, N=4096, heads=8, dh=8, inner=64, hid_lc=32, hid_f=256.
#define NPIX 4096
#define IMG 64

typedef __attribute__((ext_vector_type(8))) short bf16x8;
typedef __attribute__((ext_vector_type(4))) float floatx4;
typedef __attribute__((ext_vector_type(4))) unsigned int uintx4;

// fp32 -> (hi bf16 in low16) | (lo bf16 in high16), lo = x - f32(hi)
__device__ __forceinline__ unsigned int split_pack(float x) {
  unsigned int u = __float_as_uint(x);
  unsigned int hif = u & 0xffff0000u;
  float lof = x - __uint_as_float(hif);
  return (u >> 16) | (__float_as_uint(lof) & 0xffff0000u);
}

// pack hi16 of two floats: low16 = hi16(a), high16 = hi16(b)
__device__ __forceinline__ unsigned int hi_pair(float a, float b) {
  return (__float_as_uint(a) >> 16) | (__float_as_uint(b) & 0xffff0000u);
}

// ---------------------------------------------------------------------------
// Merged lc1+lc2 (unchanged): stage 20x20 luma halo, h1 halo in LDS,
// lc2 conv -> h2; ocg==0 also emits pooled/bsums/LN1 stats; (0,0) inits cbuf.
__global__ __launch_bounds__(256) void lc12_kernel(
    const float* __restrict__ luma, const float* __restrict__ w1,
    const float* __restrict__ b1, const float* __restrict__ w2,
    const float* __restrict__ b2, const float* __restrict__ x,
    float* __restrict__ h2, float* __restrict__ pooled,
    float* __restrict__ bsums, float* __restrict__ mu1,
    float* __restrict__ rs1, unsigned short* __restrict__ cbuf) {
  __shared__ float lum[400];      // 20x20
  __shared__ float sw1[288];      // lc1 weights 32x9
  __shared__ float tin[32][324];  // h1 on 18x18 halo per ic
  __shared__ float swt[4][32][9];
  __shared__ float red[256];
  int tile = blockIdx.x, ocg = blockIdx.y;
  int ty0 = (tile >> 2) * 16, tx0 = (tile & 3) * 16;
  int tid = threadIdx.x;
  if (tile == 0 && ocg == 0 && tid < 16) cbuf[tid] = (tid < 8) ? 0x3F80 : 0;
  for (int idx = tid; idx < 400; idx += 256) {
    int py = idx / 20, px = idx - py * 20;
    int gy = ty0 + py - 2, gx = tx0 + px - 2;
    lum[idx] = (gy >= 0 && gy < IMG && gx >= 0 && gx < IMG)
                   ? luma[gy * IMG + gx]
                   : 0.f;
  }
  for (int idx = tid; idx < 288; idx += 256) sw1[idx] = w1[idx];
  for (int idx = tid; idx < 1152; idx += 256) {
    int o = idx / 288, r = idx - o * 288;
    swt[o][r / 9][r % 9] = w2[(ocg * 4 + o) * 288 + r];
  }
  __syncthreads();
  for (int idx = tid; idx < 32 * 324; idx += 256) {
    int ic = idx / 324, pos = idx - ic * 324;
    int py = pos / 18, px = pos - py * 18;
    int gy = ty0 + py - 1, gx = tx0 + px - 1;
    float v = 0.f;
    if (gy >= 0 && gy < IMG && gx >= 0 && gx < IMG) {
      float s = b1[ic];
      const float* wp = &sw1[ic * 9];
#pragma unroll
      for (int dy = 0; dy < 3; dy++)
#pragma unroll
        for (int dx = 0; dx < 3; dx++)
          s = fmaf(wp[dy * 3 + dx], lum[(py + dy) * 20 + px + dx], s);
      v = fmaxf(s, 0.f);
    }
    tin[ic][pos] = v;
  }
  __syncthreads();
  int ly = tid >> 4, lx = tid & 15;
  int p = (ty0 + ly) * IMG + tx0 + lx;
  float acc[4];
#pragma unroll
  for (int o = 0; o < 4; o++) acc[o] = b2[ocg * 4 + o];
  for (int ic = 0; ic < 32; ic++) {
    float v[9];
#pragma unroll
    for (int dy = 0; dy < 3; dy++)
#pragma unroll
      for (int dx = 0; dx < 3; dx++)
        v[dy * 3 + dx] = tin[ic][(ly + dy) * 18 + lx + dx];
#pragma unroll
    for (int o = 0; o < 4; o++)
#pragma unroll
      for (int t = 0; t < 9; t++) acc[o] = fmaf(swt[o][ic][t], v[t], acc[o]);
  }
#pragma unroll
  for (int o = 0; o < 4; o++)
    h2[(ocg * 4 + o) * NPIX + p] = fmaxf(acc[o], 0.f);
  if (ocg == 0) {
    int gy = ty0 + ly, gx = tx0 + lx;
    float sv = 0.f;
#pragma unroll
    for (int dy = 0; dy < 3; dy++)
#pragma unroll
      for (int dx = 0; dx < 3; dx++)
        sv += lum[(ly + dy + 1) * 20 + lx + dx + 1];
    float cy = 3.f - (gy == 0 ? 1.f : 0.f) - (gy == 63 ? 1.f : 0.f);
    float cx = 3.f - (gx == 0 ? 1.f : 0.f) - (gx == 63 ? 1.f : 0.f);
    float pv = (cy * cx - sv) * (1.f / 9.f);
    pooled[p] = pv;
    red[tid] = pv;
    __syncthreads();
    for (int st = 128; st > 0; st >>= 1) {
      if (tid < st) red[tid] += red[tid + st];
      __syncthreads();
    }
    if (tid == 0) bsums[tile] = red[0];
    float s = 0.f, q = 0.f;
#pragma unroll 8
    for (int cc = 0; cc < 64; cc++) {
      float xv = x[cc * NPIX + p];
      s += xv;
      q = fmaf(xv, xv, q);
    }
    float mu = s * (1.f / 64.f);
    mu1[p] = mu;
    rs1[p] = rsqrtf(q * (1.f / 64.f) - mu * mu + 1e-5f);
  }
}

// ---------------------------------------------------------------------------
// Fused per-pixel LN (precomputed stats) + qkv 1x1 GEMM + gam/bet in-register
// + modulation + hi/lo split store. grid (128, 3). (unchanged)
__global__ __launch_bounds__(256) void ln_qkv_kernel(
    const float* __restrict__ X, const float* __restrict__ mu1,
    const float* __restrict__ rs1, const float* __restrict__ lnw,
    const float* __restrict__ lnb, const float* __restrict__ W,
    const float* __restrict__ bias, const float* __restrict__ gamW,
    const float* __restrict__ gamB, const float* __restrict__ betW,
    const float* __restrict__ betB, const float* __restrict__ h2,
    const float* __restrict__ pooled, const float* __restrict__ bsums,
    const float* __restrict__ alpha, unsigned short* __restrict__ qhl,
    unsigned short* __restrict__ khl, unsigned short* __restrict__ vthx,
    unsigned short* __restrict__ vtlx) {
  const float QSCALE = 0.35355339059327376f * 1.4426950408889634f;
  __shared__ float xs[64][32];
  __shared__ float wsh[64][64];
  __shared__ float h2s[32][32];
  __shared__ float wgs[32][64];
  __shared__ float wbs[32][64];
  __shared__ float mu[32];
  __shared__ float rs[32];
  int n0 = blockIdx.x * 32, part = blockIdx.y, m0 = part * 64;
  int tid = threadIdx.x;
  if (tid < 32) {
    mu[tid] = mu1[n0 + tid];
    rs[tid] = rs1[n0 + tid];
  }
  {
    int e = tid * 2;
    int c = e >> 3, off = (e & 7) * 4;
    *(float4*)&xs[c][off] = *(const float4*)&X[c * NPIX + n0 + off];
    int e1 = e + 1;
    int c1 = e1 >> 3, off1 = (e1 & 7) * 4;
    *(float4*)&xs[c1][off1] = *(const float4*)&X[c1 * NPIX + n0 + off1];
  }
  {
    int m = tid >> 2, kg = (tid & 3) * 16;
    const float4* wr = (const float4*)&W[(m0 + m) * 64 + kg];
    float4 w0 = wr[0], w1 = wr[1], w2 = wr[2], w3 = wr[3];
    float wv[16] = {w0.x, w0.y, w0.z, w0.w, w1.x, w1.y, w1.z, w1.w,
                    w2.x, w2.y, w2.z, w2.w, w3.x, w3.y, w3.z, w3.w};
#pragma unroll
    for (int j = 0; j < 16; j++) wsh[kg + j][m] = wv[j];
  }
  {
    int k = tid >> 3, nf = (tid & 7) * 4;
    *(float4*)&h2s[k][nf] = *(const float4*)&h2[k * NPIX + n0 + nf];
  }
  {
    int m = tid >> 2, kg = (tid & 3) * 8;
    const float4* g0 = (const float4*)&gamW[m * 32 + kg];
    float4 a = g0[0], b4 = g0[1];
    float gv[8] = {a.x, a.y, a.z, a.w, b4.x, b4.y, b4.z, b4.w};
#pragma unroll
    for (int j = 0; j < 8; j++) wgs[kg + j][m] = gv[j];
    const float4* bb0 = (const float4*)&betW[m * 32 + kg];
    float4 c4 = bb0[0], d4 = bb0[1];
    float bv[8] = {c4.x, c4.y, c4.z, c4.w, d4.x, d4.y, d4.z, d4.w};
#pragma unroll
    for (int j = 0; j < 8; j++) wbs[kg + j][m] = bv[j];
  }
  __syncthreads();
  {
    int c = tid >> 2, pg = (tid & 3) * 8;
    float wc = lnw[c], bc = lnb[c];
#pragma unroll
    for (int j = 0; j < 8; j++) {
      int p = pg + j;
      xs[c][p] = (xs[c][p] - mu[p]) * rs[p] * wc + bc;
    }
  }
  __syncthreads();
  int tx = tid & 15, ty = tid >> 4;
  float ga[4][2] = {}, ba[4][2] = {};
#pragma unroll 8
  for (int kk = 0; kk < 32; kk++) {
    float4 wg4 = *(const float4*)&wgs[kk][ty * 4];
    float4 wb4 = *(const float4*)&wbs[kk][ty * 4];
    float2 h22 = *(const float2*)&h2s[kk][tx * 2];
    float gv[4] = {wg4.x, wg4.y, wg4.z, wg4.w};
    float bv[4] = {wb4.x, wb4.y, wb4.z, wb4.w};
    float hv[2] = {h22.x, h22.y};
#pragma unroll
    for (int im = 0; im < 4; im++)
#pragma unroll
      for (int in = 0; in < 2; in++) {
        ga[im][in] = fmaf(gv[im], hv[in], ga[im][in]);
        ba[im][in] = fmaf(bv[im], hv[in], ba[im][in]);
      }
  }
#pragma unroll
  for (int im = 0; im < 4; im++) {
    int cc = ty * 4 + im;
    float gb = gamB[cc], bb2 = betB[cc];
#pragma unroll
    for (int in = 0; in < 2; in++) {
      ga[im][in] += gb;
      ba[im][in] += bb2;
    }
  }
  float acc[4][2] = {};
#pragma unroll 8
  for (int kk = 0; kk < 64; kk++) {
    float4 a = *(const float4*)&wsh[kk][ty * 4];
    float2 b2 = *(const float2*)&xs[kk][tx * 2];
    float av[4] = {a.x, a.y, a.z, a.w};
    float bv[2] = {b2.x, b2.y};
#pragma unroll
    for (int im = 0; im < 4; im++)
#pragma unroll
      for (int in = 0; in < 2; in++)
        acc[im][in] = fmaf(av[im], bv[in], acc[im][in]);
  }
  float val[4][2];
#pragma unroll
  for (int im = 0; im < 4; im++) {
    int cc = ty * 4 + im;
    float bv = bias[m0 + cc];
#pragma unroll
    for (int in = 0; in < 2; in++)
      val[im][in] = fmaf(ga[im][in], acc[im][in] + bv, ba[im][in]);
  }
  if (part == 0) {
    float msum = 0.f;
#pragma unroll
    for (int t = 0; t < 16; t++) msum += bsums[t];
    float mean = msum * (1.f / 4096.f);
    float a0 = alpha[0];
    const float2 pv = *(const float2*)&pooled[n0 + tx * 2];
    float iv[2] = {a0 * (pv.x - mean), a0 * (pv.y - mean)};
#pragma unroll
    for (int im = 0; im < 4; im++)
#pragma unroll
      for (int in = 0; in < 2; in++)
        val[im][in] = (val[im][in] + iv[in]) * QSCALE;
  }
  if (part < 2) {
    unsigned short* dst = (part == 0) ? qhl : khl;
    int h = ty >> 1, d0 = (ty & 1) * 4;
#pragma unroll
    for (int in = 0; in < 2; in++) {
      int n = n0 + tx * 2 + in;
      unsigned int pk[4];
#pragma unroll
      for (int im = 0; im < 4; im++) pk[im] = split_pack(val[im][in]);
      short4 hi, lo;
      hi.x = (short)(pk[0] & 0xffffu); hi.y = (short)(pk[1] & 0xffffu);
      hi.z = (short)(pk[2] & 0xffffu); hi.w = (short)(pk[3] & 0xffffu);
      lo.x = (short)(pk[0] >> 16); lo.y = (short)(pk[1] >> 16);
      lo.z = (short)(pk[2] >> 16); lo.w = (short)(pk[3] >> 16);
      unsigned short* base = dst + ((size_t)(h * NPIX + n) << 4) + d0;
      *(short4*)base = hi;
      *(short4*)(base + 8) = lo;
    }
  } else {
    int nq = n0 + tx * 2;
    int off0 = (nq >> 5) * 32 + ((nq >> 4) & 1) * 4 + ((nq >> 2) & 3) * 8 +
               (nq & 3);
#pragma unroll
    for (int im = 0; im < 4; im++) {
      int cc = ty * 4 + im;
      unsigned int pk0 = split_pack(val[im][0]);
      unsigned int pk1 = split_pack(val[im][1]);
      short2 hi, lo;
      hi.x = (short)(pk0 & 0xffffu);
      hi.y = (short)(pk1 & 0xffffu);
      lo.x = (short)(pk0 >> 16);
      lo.y = (short)(pk1 >> 16);
      *(short2*)(vthx + (size_t)cc * NPIX + off0) = hi;
      *(short2*)(vtlx + (size_t)cc * NPIX + off0) = lo;
    }
  }
}

// ---------------------------------------------------------------------------
// MFMA flash attention (unchanged): 4 i-tiles/wave, JP=8, zero LDS, unroll 4.
// grid (16 i-tiles of 256, 8 heads, 8 jp).
__global__ __launch_bounds__(256, 4) void attn_kernel(
    const unsigned short* __restrict__ qhl,
    const unsigned short* __restrict__ khl,
    const unsigned short* __restrict__ vthx,
    const unsigned short* __restrict__ vtlx,
    const unsigned short* __restrict__ cbuf, float* __restrict__ pacc,
    float* __restrict__ pl) {
  int tid = threadIdx.x;
  int wave = tid >> 6, lane = tid & 63;
  int g = lane >> 4, c = lane & 15;
  int h = blockIdx.y, jp = blockIdx.z;
  int i0 = blockIdx.x * 256 + wave * 64;
  int jbase = jp * 512;
  bf16x8 qB[4];
#pragma unroll
  for (int t = 0; t < 4; t++)
    qB[t] = *(const bf16x8*)(qhl + ((size_t)(h * NPIX + i0 + t * 16 + c) << 4) +
                             ((g & 1) << 3));
  const unsigned short* kp =
      khl + ((size_t)(h * NPIX + jbase + c) << 4) + ((g >> 1) << 3);
  const unsigned short* vhp;
  const unsigned short* vlp;
  int vstep;
  if (c < 8) {
    vhp = vthx + (size_t)(h * 8 + c) * NPIX + jbase + (g << 3);
    vlp = vtlx + (size_t)(h * 8 + c) * NPIX + jbase + (g << 3);
    vstep = 32;
  } else {
    vhp = (c == 8) ? cbuf : (cbuf + 8);  // ones row / zero rows
    vlp = cbuf + 8;
    vstep = 0;
  }
  floatx4 zero4 = {0.f, 0.f, 0.f, 0.f};
  floatx4 aH[4], aM[4];
#pragma unroll
  for (int t = 0; t < 4; t++) {
    aH[t] = zero4;
    aM[t] = zero4;
  }
#pragma unroll 4
  for (int jt = 0; jt < 16; ++jt) {
    bf16x8 ka0 = *(const bf16x8*)kp;
    bf16x8 ka1 = *(const bf16x8*)(kp + 256);
    bf16x8 avh = *(const bf16x8*)vhp;
    bf16x8 avl = *(const bf16x8*)vlp;
    kp += 512;
    vhp += vstep;
    vlp += vstep;
#pragma unroll
    for (int t = 0; t < 4; t++) {
      floatx4 s0 =
          __builtin_amdgcn_mfma_f32_16x16x32_bf16(ka0, qB[t], zero4, 0, 0, 0);
      floatx4 s1 =
          __builtin_amdgcn_mfma_f32_16x16x32_bf16(ka1, qB[t], zero4, 0, 0, 0);
      float p0 = __builtin_amdgcn_exp2f(fminf(s0[0], 80.f));
      float p1 = __builtin_amdgcn_exp2f(fminf(s0[1], 80.f));
      float p2 = __builtin_amdgcn_exp2f(fminf(s0[2], 80.f));
      float p3 = __builtin_amdgcn_exp2f(fminf(s0[3], 80.f));
      float p4 = __builtin_amdgcn_exp2f(fminf(s1[0], 80.f));
      float p5 = __builtin_amdgcn_exp2f(fminf(s1[1], 80.f));
      float p6 = __builtin_amdgcn_exp2f(fminf(s1[2], 80.f));
      float p7 = __builtin_amdgcn_exp2f(fminf(s1[3], 80.f));
      uintx4 bh;
      bh.x = hi_pair(p0, p1);
      bh.y = hi_pair(p2, p3);
      bh.z = hi_pair(p4, p5);
      bh.w = hi_pair(p6, p7);
      bf16x8 pbh = __builtin_bit_cast(bf16x8, bh);
      aH[t] = __builtin_amdgcn_mfma_f32_16x16x32_bf16(avh, pbh, aH[t], 0, 0, 0);
      aM[t] = __builtin_amdgcn_mfma_f32_16x16x32_bf16(avl, pbh, aM[t], 0, 0, 0);
    }
  }
#pragma unroll
  for (int t = 0; t < 4; t++) {
    floatx4 o = aH[t] + aM[t];
    if (g < 2) {
      size_t b0 = (size_t)((jp * 8 + h) * NPIX + i0 + t * 16 + c);
      *(float4*)&pacc[b0 * 8 + g * 4] = make_float4(o[0], o[1], o[2], o[3]);
    } else if (g == 2) {
      pl[(size_t)((jp * 8 + h) * NPIX + i0 + t * 16 + c)] = o[0];
    }
  }
}

// ---------------------------------------------------------------------------
// Fused: combine 8 j-partitions -> proj GEMM + residual -> x1 (ch==0) + LN2
// stats -> LN -> one 64-ch slice of ffn1 -> f1. grid (128, 4).
// W1 now has its own LDS buffer, staged up-front (overlaps combine/GEMM);
// barriers 5 -> 3.
__global__ __launch_bounds__(256) void proj_ffn1_kernel(
    const float* __restrict__ pacc, const float* __restrict__ pl,
    const float* __restrict__ Wp, const float* __restrict__ bp,
    const float* __restrict__ x, const float* __restrict__ ln2w,
    const float* __restrict__ ln2b, const float* __restrict__ W1,
    const float* __restrict__ b1f, float* __restrict__ x1,
    float* __restrict__ f1) {
  __shared__ float at[64][33];
  __shared__ float wsh[64][64];
  __shared__ float w1s[64][64];
  __shared__ float xsl[64][33];
  __shared__ float ps[8][33];
  __shared__ float pq[8][33];
  __shared__ float mus[32];
  __shared__ float rss[32];
  int n0 = blockIdx.x * 32;
  int ch = blockIdx.y;
  int tid = threadIdx.x;
  {
    int mm = tid >> 2, kg = (tid & 3) * 16;
    const float4* wr = (const float4*)&Wp[mm * 64 + kg];
    float4 w0 = wr[0], w1 = wr[1], w2 = wr[2], w3 = wr[3];
    float wv[16] = {w0.x, w0.y, w0.z, w0.w, w1.x, w1.y, w1.z, w1.w,
                    w2.x, w2.y, w2.z, w2.w, w3.x, w3.y, w3.z, w3.w};
#pragma unroll
    for (int j = 0; j < 16; j++) wsh[kg + j][mm] = wv[j];
    const float4* w1r = (const float4*)&W1[(ch * 64 + mm) * 64 + kg];
    float4 u0 = w1r[0], u1 = w1r[1], u2 = w1r[2], u3 = w1r[3];
    float uv[16] = {u0.x, u0.y, u0.z, u0.w, u1.x, u1.y, u1.z, u1.w,
                    u2.x, u2.y, u2.z, u2.w, u3.x, u3.y, u3.z, u3.w};
#pragma unroll
    for (int j = 0; j < 16; j++) w1s[kg + j][mm] = uv[j];
  }
  {
    int hh = tid >> 5, nn = tid & 31;
    int i = n0 + nn;
    float L = 0.f, o[8] = {};
#pragma unroll
    for (int p = 0; p < 8; p++) {
      size_t base = (size_t)((p * 8 + hh) * NPIX + i);
      L += pl[base];
      const float4 a0 = *(const float4*)&pacc[base * 8];
      const float4 a1 = *(const float4*)&pacc[base * 8 + 4];
      o[0] += a0.x; o[1] += a0.y; o[2] += a0.z; o[3] += a0.w;
      o[4] += a1.x; o[5] += a1.y; o[6] += a1.z; o[7] += a1.w;
    }
    float inv = 1.f / L;
#pragma unroll
    for (int d = 0; d < 8; d++) at[hh * 8 + d][nn] = o[d] * inv;
  }
  __syncthreads();
  int ty = tid >> 5, tx = tid & 31;
  float acc[8] = {};
#pragma unroll 8
  for (int k = 0; k < 64; k++) {
    float b = at[k][tx];
    float4 a0 = *(const float4*)&wsh[k][ty * 8];
    float4 a1 = *(const float4*)&wsh[k][ty * 8 + 4];
    acc[0] = fmaf(a0.x, b, acc[0]);
    acc[1] = fmaf(a0.y, b, acc[1]);
    acc[2] = fmaf(a0.z, b, acc[2]);
    acc[3] = fmaf(a0.w, b, acc[3]);
    acc[4] = fmaf(a1.x, b, acc[4]);
    acc[5] = fmaf(a1.y, b, acc[5]);
    acc[6] = fmaf(a1.z, b, acc[6]);
    acc[7] = fmaf(a1.w, b, acc[7]);
  }
  float v[8], sn = 0.f, qn = 0.f;
#pragma unroll
  for (int im = 0; im < 8; im++) {
    int row = ty * 8 + im;
    float vv = acc[im] + bp[row] + x[row * NPIX + n0 + tx];
    v[im] = vv;
    sn += vv;
    qn = fmaf(vv, vv, qn);
  }
  if (ch == 0) {
#pragma unroll
    for (int im = 0; im < 8; im++)
      x1[(ty * 8 + im) * NPIX + n0 + tx] = v[im];
  }
  ps[ty][tx] = sn;
  pq[ty][tx] = qn;
  __syncthreads();
  if (tid < 32) {
    float s = 0.f, q = 0.f;
#pragma unroll
    for (int t = 0; t < 8; t++) {
      s += ps[t][tid];
      q += pq[t][tid];
    }
    float mu = s * (1.f / 64.f);
    mus[tid] = mu;
    rss[tid] = rsqrtf(q * (1.f / 64.f) - mu * mu + 1e-5f);
  }
  __syncthreads();
  {
    float muv = mus[tx], rsv = rss[tx];
#pragma unroll
    for (int im = 0; im < 8; im++) {
      int row = ty * 8 + im;
      xsl[row][tx] = (v[im] - muv) * rsv * ln2w[row] + ln2b[row];
    }
  }
  __syncthreads();
  float a2[8] = {};
#pragma unroll 8
  for (int k = 0; k < 64; k++) {
    float b = xsl[k][tx];
    float4 a0 = *(const float4*)&w1s[k][ty * 8];
    float4 a1 = *(const float4*)&w1s[k][ty * 8 + 4];
    a2[0] = fmaf(a0.x, b, a2[0]);
    a2[1] = fmaf(a0.y, b, a2[1]);
    a2[2] = fmaf(a0.z, b, a2[2]);
    a2[3] = fmaf(a0.w, b, a2[3]);
    a2[4] = fmaf(a1.x, b, a2[4]);
    a2[5] = fmaf(a1.y, b, a2[5]);
    a2[6] = fmaf(a1.z, b, a2[6]);
    a2[7] = fmaf(a1.w, b, a2[7]);
  }
#pragma unroll
  for (int im = 0; im < 8; im++) {
    int row = ch * 64 + ty * 8 + im;
    f1[row * NPIX + n0 + tx] = a2[im] + b1f[row];
  }
}

// ---------------------------------------------------------------------------
// Merged dw_gelu + ffn2, 16-px tiles (unchanged from r13).
// grid (256 n-tiles of 16 px, 2 m-halves of 32).
__global__ __launch_bounds__(256) void ffn2_dw_kernel(
    const float* __restrict__ f1, const float* __restrict__ dww,
    const float* __restrict__ dwb, const float* __restrict__ W,
    const float* __restrict__ bias, const float* __restrict__ resid,
    float* __restrict__ C) {
  __shared__ float xs[256][20];   // f2 tile [k=ch][px], stride 20
  __shared__ float wsh[256][33];  // W [k][m], stride 33
  int n0 = blockIdx.x * 16, m0 = blockIdx.y * 32;
  int tid = threadIdx.x;
  int y = n0 >> 6, x0 = n0 & 63;
#pragma unroll
  for (int e = tid; e < 8192; e += 256) {
    int mm = e >> 8, kk = e & 255;
    wsh[kk][mm] = W[(m0 + mm) * 256 + kk];
  }
  {
    int px4 = (tid & 3) * 4;
    int xabs = x0 + px4;
#pragma unroll
    for (int k = 0; k < 4; k++) {
      int c = (tid >> 2) + 64 * k;
      const float* base = f1 + c * NPIX;
      float wv[9];
#pragma unroll
      for (int i = 0; i < 9; i++) wv[i] = dww[c * 9 + i];
      float bc = dwb[c];
      float a[4] = {bc, bc, bc, bc};
#pragma unroll
      for (int dy = 0; dy < 3; dy++) {
        int yy = y + dy - 1;
        if (yy < 0 || yy > 63) continue;
        const float* row = base + yy * IMG + xabs;
        float4 mid = *(const float4*)row;
        float left = (xabs > 0) ? row[-1] : 0.f;
        float right = (xabs + 4 < IMG) ? row[4] : 0.f;
        float win[6] = {left, mid.x, mid.y, mid.z, mid.w, right};
#pragma unroll
        for (int o = 0; o < 4; o++)
#pragma unroll
          for (int dx = 0; dx < 3; dx++)
            a[o] = fmaf(wv[dy * 3 + dx], win[o + dx], a[o]);
      }
      float4 o4;
      float* op = &o4.x;
#pragma unroll
      for (int o = 0; o < 4; o++)
        op[o] = 0.5f * a[o] * (1.f + erff(a[o] * 0.70710678118654752f));
      *(float4*)&xs[c][px4] = o4;
    }
  }
  __syncthreads();
  int m = tid >> 3, np = (tid & 7) * 2;
  float a0 = 0.f, a1 = 0.f;
#pragma unroll 8
  for (int kk = 0; kk < 256; kk++) {
    float w0 = wsh[kk][m];
    float b0 = xs[kk][np];
    float b1 = xs[kk][np + 1];
    a0 = fmaf(w0, b0, a0);
    a1 = fmaf(w0, b1, a1);
  }
  int row = m0 + m;
  float bv = bias[row];
  const float2 rr = *(const float2*)&resid[row * NPIX + n0 + np];
  *(float2*)&C[row * NPIX + n0 + np] =
      make_float2(a0 + bv + rr.x, a1 + bv + rr.y);
}

// ---------------------------------------------------------------------------
extern "C" void kernel_launch(void* const* d_in, const int* in_sizes, int n_in,
                              void* d_out, int out_size, void* d_ws,
                              size_t ws_size, hipStream_t stream) {
  const float* x      = (const float*)d_in[0];
  const float* luma   = (const float*)d_in[1];
  const float* ln1_w  = (const float*)d_in[2];
  const float* ln1_b  = (const float*)d_in[3];
  const float* qkv_w  = (const float*)d_in[4];
  const float* qkv_b  = (const float*)d_in[5];
  const float* proj_w = (const float*)d_in[6];
  const float* proj_b = (const float*)d_in[7];
  const float* lc1_w  = (const float*)d_in[8];
  const float* lc1_b  = (const float*)d_in[9];
  const float* lc2_w  = (const float*)d_in[10];
  const float* lc2_b  = (const float*)d_in[11];
  const float* gam_w  = (const float*)d_in[12];
  const float* gam_b  = (const float*)d_in[13];
  const float* bet_w  = (const float*)d_in[14];
  const float* bet_b  = (const float*)d_in[15];
  const float* alpha  = (const float*)d_in[16];
  const float* ln2_w  = (const float*)d_in[17];
  const float* ln2_b  = (const float*)d_in[18];
  const float* ffn1_w = (const float*)d_in[19];
  const float* ffn1_b = (const float*)d_in[20];
  const float* dw_w   = (const float*)d_in[21];
  const float* dw_b   = (const float*)d_in[22];
  const float* ffn2_w = (const float*)d_in[23];
  const float* ffn2_b = (const float*)d_in[24];
  float* out = (float*)d_out;

  float* w = (float*)d_ws;
  float* pooled = w + 0;        // 4096
  float* bsums  = w + 4096;     // 64 (16 used)
  unsigned short* cbuf = (unsigned short*)(w + 4160);     // 64 f (16 us used)
  float* mu1 = w + 4224;        // 4096
  float* rs1 = w + 8320;        // 4096
  unsigned short* qhl  = (unsigned short*)(w + 12416);    // 262144 f
  unsigned short* khl  = (unsigned short*)(w + 274560);   // 262144 f
  unsigned short* vthx = (unsigned short*)(w + 536704);   // 131072 f
  unsigned short* vtlx = (unsigned short*)(w + 667776);   // 131072 f
  float* pacc = w + 798848;    // 2097152 (JP=8)
  float* pl   = w + 2896000;   // 262144
  float* x1   = w + 3158144;   // 262144
  float* f1   = w + 3420288;   // 1048576
  float* h2   = w + 4468864;   // 131072

  lc12_kernel<<<dim3(16, 8), 256, 0, stream>>>(luma, lc1_w, lc1_b, lc2_w,
                                               lc2_b, x, h2, pooled, bsums,
                                               mu1, rs1, cbuf);
  ln_qkv_kernel<<<dim3(128, 3), 256, 0, stream>>>(
      x, mu1, rs1, ln1_w, ln1_b, qkv_w, qkv_b, gam_w, gam_b, bet_w, bet_b, h2,
      pooled, bsums, alpha, qhl, khl, vthx, vtlx);
  attn_kernel<<<dim3(16, 8, 8), 256, 0, stream>>>(qhl, khl, vthx, vtlx, cbuf,
                                                  pacc, pl);
  proj_ffn1_kernel<<<dim3(128, 4), 256, 0, stream>>>(
      pacc, pl, proj_w, proj_b, x, ln2_w, ln2_b, ffn1_w, ffn1_b, x1, f1);
  ffn2_dw_kernel<<<dim3(256, 2), 256, 0, stream>>>(f1, dw_w, dw_b, ffn2_w,
                                                   ffn2_b, x1, out);
}